// Round 1
// baseline (745.988 us; speedup 1.0000x reference)
//
#include <hip/hip_runtime.h>
#include <hip/hip_bf16.h>

#define FI 64
#define FO 63
#define FP 64
#define NZPW 8
#define INV_TAU 20.0f

// ---------------- MLP (n_func): x (n,64) -> x1 padded (n,64) ----------------
__global__ __launch_bounds__(256) void k_mlp_n(
    const float* __restrict__ x,
    const float* __restrict__ W1, const float* __restrict__ b1,
    const float* __restrict__ W2, const float* __restrict__ b2,
    float* __restrict__ x1p, int n)
{
    int t = blockIdx.x * 256 + threadIdx.x;
    if (t >= n) return;
    const float* xr = x + (size_t)t * FI;

    float h[FO];
#pragma unroll
    for (int j = 0; j < FO; ++j) h[j] = b1[j];
#pragma unroll 1
    for (int ii = 0; ii < FI; ii += 4) {
        float4 xq = *(const float4*)(xr + ii);
#pragma unroll
        for (int j = 0; j < FO; ++j) h[j] = fmaf(xq.x, W1[(ii+0)*FO+j], h[j]);
#pragma unroll
        for (int j = 0; j < FO; ++j) h[j] = fmaf(xq.y, W1[(ii+1)*FO+j], h[j]);
#pragma unroll
        for (int j = 0; j < FO; ++j) h[j] = fmaf(xq.z, W1[(ii+2)*FO+j], h[j]);
#pragma unroll
        for (int j = 0; j < FO; ++j) h[j] = fmaf(xq.w, W1[(ii+3)*FO+j], h[j]);
    }
#pragma unroll
    for (int j = 0; j < FO; ++j) h[j] = fmaxf(h[j], 0.f);

    float o[FO];
#pragma unroll
    for (int j = 0; j < FO; ++j) o[j] = b2[j];
#pragma unroll 1
    for (int i = 0; i < FO; ++i) {
        float hi = h[i];
#pragma unroll
        for (int j = 0; j < FO; ++j) o[j] = fmaf(hi, W2[i*FO+j], o[j]);
    }

    float* dst = x1p + (size_t)t * FP;
#pragma unroll
    for (int c = 0; c < 15; ++c) {
        float4 w;
        w.x = fmaxf(o[4*c+0], 0.f);
        w.y = fmaxf(o[4*c+1], 0.f);
        w.z = fmaxf(o[4*c+2], 0.f);
        w.w = fmaxf(o[4*c+3], 0.f);
        ((float4*)dst)[c] = w;
    }
    {
        float4 w;
        w.x = fmaxf(o[60], 0.f);
        w.y = fmaxf(o[61], 0.f);
        w.z = fmaxf(o[62], 0.f);
        w.w = 0.f;  // pad column stays zero
        ((float4*)dst)[15] = w;
    }
}

// ---------------- spmm: acc[row] += val * xin[col]  (COO, atomics) ----------
// one wave per nnz entry, lane = feature (padded to 64; pad contributes 0.0)
__global__ __launch_bounds__(256) void k_spmm(
    const int* __restrict__ rows, const int* __restrict__ cols,
    const float* __restrict__ val, const float* __restrict__ xin,
    float* __restrict__ acc, int nnz)
{
    int wave = blockIdx.x * 4 + (threadIdx.x >> 6);
    int lane = threadIdx.x & 63;
    int e0 = wave * NZPW;
#pragma unroll 1
    for (int k = 0; k < NZPW; ++k) {
        int e = e0 + k;
        if (e >= nnz) break;
        int r = rows[e];
        int c = cols[e];
        float v = val[e];
        float xv = xin[((size_t)c << 6) + lane];
        unsafeAtomicAdd(&acc[((size_t)r << 6) + lane], v * xv);
    }
}

// ------- combine: recompute self-MLP, add spmm2 result, classifier dot ------
__global__ __launch_bounds__(256) void k_combine(
    const float* __restrict__ x,
    const float* __restrict__ W1, const float* __restrict__ b1,
    const float* __restrict__ W2, const float* __restrict__ b2,
    const float* __restrict__ Wc, const float* __restrict__ bcp,
    const float* __restrict__ x2b,
    float* __restrict__ out, float* __restrict__ x3, int n)
{
    int t = blockIdx.x * 256 + threadIdx.x;
    if (t >= n) return;
    const float* xr = x + (size_t)t * FI;

    float h[FO];
#pragma unroll
    for (int j = 0; j < FO; ++j) h[j] = b1[j];
#pragma unroll 1
    for (int ii = 0; ii < FI; ii += 4) {
        float4 xq = *(const float4*)(xr + ii);
#pragma unroll
        for (int j = 0; j < FO; ++j) h[j] = fmaf(xq.x, W1[(ii+0)*FO+j], h[j]);
#pragma unroll
        for (int j = 0; j < FO; ++j) h[j] = fmaf(xq.y, W1[(ii+1)*FO+j], h[j]);
#pragma unroll
        for (int j = 0; j < FO; ++j) h[j] = fmaf(xq.z, W1[(ii+2)*FO+j], h[j]);
#pragma unroll
        for (int j = 0; j < FO; ++j) h[j] = fmaf(xq.w, W1[(ii+3)*FO+j], h[j]);
    }
#pragma unroll
    for (int j = 0; j < FO; ++j) h[j] = fmaxf(h[j], 0.f);

    float o[FO];
#pragma unroll
    for (int j = 0; j < FO; ++j) o[j] = b2[j];
#pragma unroll 1
    for (int i = 0; i < FO; ++i) {
        float hi = h[i];
#pragma unroll
        for (int j = 0; j < FO; ++j) o[j] = fmaf(hi, W2[i*FO+j], o[j]);
    }

    const float4* q4 = (const float4*)(x2b + (size_t)t * FP);
    float4* dst = (float4*)(out + (size_t)t * FP);
    float dot = 0.f;
#pragma unroll
    for (int c = 0; c < 15; ++c) {
        float4 q = q4[c];
        float4 w;
        w.x = q.x + fmaxf(o[4*c+0], 0.f);
        w.y = q.y + fmaxf(o[4*c+1], 0.f);
        w.z = q.z + fmaxf(o[4*c+2], 0.f);
        w.w = q.w + fmaxf(o[4*c+3], 0.f);
        dot = fmaf(w.x, Wc[4*c+0], dot);
        dot = fmaf(w.y, Wc[4*c+1], dot);
        dot = fmaf(w.z, Wc[4*c+2], dot);
        dot = fmaf(w.w, Wc[4*c+3], dot);
        dst[c] = w;
    }
    {
        float4 q = q4[15];
        float4 w;
        w.x = q.x + fmaxf(o[60], 0.f);
        w.y = q.y + fmaxf(o[61], 0.f);
        w.z = q.z + fmaxf(o[62], 0.f);
        w.w = 0.f;  // slot for sinkhorn channel (overwritten later)
        dot = fmaf(w.x, Wc[60], dot);
        dot = fmaf(w.y, Wc[61], dot);
        dot = fmaf(w.z, Wc[62], dot);
        dst[15] = w;
    }
    x3[t] = dot + bcp[0];
}

// ---------------- sinkhorn: 256x256, 20 iters, single block ----------------
// X[a][b] = x3[a*256+b]. Even iters: LSE over a (per b). Odd: over b (per a).
// Output lands back at x3's own flat index, channel 63 of out.
__global__ __launch_bounds__(1024) void k_sinkhorn(
    const float* __restrict__ x3, float* __restrict__ out)
{
    __shared__ float2 part[32][256];
    __shared__ float lse[256];
    int tid = threadIdx.x;
    int ta = tid >> 5;    // row tile  (a = ta*8 + i)
    int tb = tid & 31;    // col tile  (b = tb*8 + j)

    float v[8][8];
#pragma unroll
    for (int i = 0; i < 8; ++i) {
        const float4* src = (const float4*)(x3 + (ta*8 + i)*256 + tb*8);
        float4 a0 = src[0], a1 = src[1];
        v[i][0] = a0.x * INV_TAU; v[i][1] = a0.y * INV_TAU;
        v[i][2] = a0.z * INV_TAU; v[i][3] = a0.w * INV_TAU;
        v[i][4] = a1.x * INV_TAU; v[i][5] = a1.y * INV_TAU;
        v[i][6] = a1.z * INV_TAU; v[i][7] = a1.w * INV_TAU;
    }

#pragma unroll 1
    for (int it = 0; it < 20; ++it) {
        if ((it & 1) == 0) {
            // normalize over a: per column b, LSE across i (local) then ta (LDS)
#pragma unroll
            for (int j = 0; j < 8; ++j) {
                float m = v[0][j];
#pragma unroll
                for (int i = 1; i < 8; ++i) m = fmaxf(m, v[i][j]);
                float s = 0.f;
#pragma unroll
                for (int i = 0; i < 8; ++i) s += __expf(v[i][j] - m);
                part[ta][tb*8 + j] = make_float2(m, s);
            }
            __syncthreads();
            if (tid < 256) {
                float M = -1e30f, S = 0.f;
#pragma unroll 1
                for (int k = 0; k < 32; ++k) {
                    float2 p = part[k][tid];
                    float nm = fmaxf(M, p.x);
                    S = S * __expf(M - nm) + p.y * __expf(p.x - nm);
                    M = nm;
                }
                lse[tid] = M + __logf(S);
            }
            __syncthreads();
#pragma unroll
            for (int j = 0; j < 8; ++j) {
                float l = lse[tb*8 + j];
#pragma unroll
                for (int i = 0; i < 8; ++i) v[i][j] -= l;
            }
            __syncthreads();
        } else {
            // normalize over b: per row a, LSE across j (local) then tb (LDS)
#pragma unroll
            for (int i = 0; i < 8; ++i) {
                float m = v[i][0];
#pragma unroll
                for (int j = 1; j < 8; ++j) m = fmaxf(m, v[i][j]);
                float s = 0.f;
#pragma unroll
                for (int j = 0; j < 8; ++j) s += __expf(v[i][j] - m);
                part[tb][ta*8 + i] = make_float2(m, s);
            }
            __syncthreads();
            if (tid < 256) {
                float M = -1e30f, S = 0.f;
#pragma unroll 1
                for (int k = 0; k < 32; ++k) {
                    float2 p = part[k][tid];
                    float nm = fmaxf(M, p.x);
                    S = S * __expf(M - nm) + p.y * __expf(p.x - nm);
                    M = nm;
                }
                lse[tid] = M + __logf(S);
            }
            __syncthreads();
#pragma unroll
            for (int i = 0; i < 8; ++i) {
                float l = lse[ta*8 + i];
#pragma unroll
                for (int j = 0; j < 8; ++j) v[i][j] -= l;
            }
            __syncthreads();
        }
    }

#pragma unroll
    for (int i = 0; i < 8; ++i) {
        int a = ta*8 + i;
#pragma unroll
        for (int j = 0; j < 8; ++j) {
            out[((size_t)(a*256 + tb*8 + j) << 6) + 63] = __expf(v[i][j]);
        }
    }
}

extern "C" void kernel_launch(void* const* d_in, const int* in_sizes, int n_in,
                              void* d_out, int out_size, void* d_ws, size_t ws_size,
                              hipStream_t stream)
{
    const float* K_value = (const float*)d_in[0];
    const int*   K_index = (const int*)d_in[1];
    const float* A_value = (const float*)d_in[2];
    const int*   A_index = (const int*)d_in[3];
    const float* x   = (const float*)d_in[4];
    const float* Wn1 = (const float*)d_in[5];
    const float* bn1 = (const float*)d_in[6];
    const float* Wn2 = (const float*)d_in[7];
    const float* bn2 = (const float*)d_in[8];
    const float* Ws1 = (const float*)d_in[9];
    const float* bs1 = (const float*)d_in[10];
    const float* Ws2 = (const float*)d_in[11];
    const float* bs2 = (const float*)d_in[12];
    const float* Wc  = (const float*)d_in[13];
    const float* bc  = (const float*)d_in[14];

    int nnzK = in_sizes[0];
    int nnzA = in_sizes[2];
    int n    = in_sizes[4] / FI;   // 65536

    float* outf = (float*)d_out;
    char*  ws   = (char*)d_ws;
    float* bufA = (float*)ws;                        // x1 (padded), later x2 accumulator
    float* x3   = (float*)(ws + (size_t)n * FP * 4); // n floats
    float* Wx   = outf;                              // reuse d_out as Wx accumulator

    // 1. zero Wx accumulator (lives in d_out)
    hipMemsetAsync(Wx, 0, (size_t)n * FP * 4, stream);
    // 2. n_func MLP -> bufA (x1, padded to 64)
    k_mlp_n<<<(n + 255) / 256, 256, 0, stream>>>(x, Wn1, bn1, Wn2, bn2, bufA, n);
    // 3. Wx += K @ x1
    int blocks1 = (nnzK + 4 * NZPW - 1) / (4 * NZPW);
    k_spmm<<<blocks1, 256, 0, stream>>>(K_index, K_index + nnzK, K_value, bufA, Wx, nnzK);
    // 4. re-zero bufA (becomes x2 accumulator)
    hipMemsetAsync(bufA, 0, (size_t)n * FP * 4, stream);
    // 5. x2 += A @ Wx
    int blocks2 = (nnzA + 4 * NZPW - 1) / (4 * NZPW);
    k_spmm<<<blocks2, 256, 0, stream>>>(A_index, A_index + nnzA, A_value, Wx, bufA, nnzA);
    // 6. combine: self-MLP + x2, write out[:, :63], classifier -> x3
    k_combine<<<(n + 255) / 256, 256, 0, stream>>>(x, Ws1, bs1, Ws2, bs2, Wc, bc,
                                                   bufA, outf, x3, n);
    // 7. sinkhorn -> out[:, 63]
    k_sinkhorn<<<1, 1024, 0, stream>>>(x3, outf);
}

// Round 3
// 649.807 us; speedup vs baseline: 1.1480x; 1.1480x over previous
//
#include <hip/hip_runtime.h>
#include <hip/hip_bf16.h>

#define FI 64
#define FO 63
#define FP 64
#define NZPW 8
#define INV_TAU 20.0f
#define LOG2E 1.4426950408889634f

// ---------------- MLP (n_func): x (n,64) -> x1 padded (n,64) ----------------
__global__ __launch_bounds__(256) void k_mlp_n(
    const float* __restrict__ x,
    const float* __restrict__ W1, const float* __restrict__ b1,
    const float* __restrict__ W2, const float* __restrict__ b2,
    float* __restrict__ x1p, int n)
{
    int t = blockIdx.x * 256 + threadIdx.x;
    if (t >= n) return;
    const float* xr = x + (size_t)t * FI;

    float h[FO];
#pragma unroll
    for (int j = 0; j < FO; ++j) h[j] = b1[j];
#pragma unroll 1
    for (int ii = 0; ii < FI; ii += 4) {
        float4 xq = *(const float4*)(xr + ii);
#pragma unroll
        for (int j = 0; j < FO; ++j) h[j] = fmaf(xq.x, W1[(ii+0)*FO+j], h[j]);
#pragma unroll
        for (int j = 0; j < FO; ++j) h[j] = fmaf(xq.y, W1[(ii+1)*FO+j], h[j]);
#pragma unroll
        for (int j = 0; j < FO; ++j) h[j] = fmaf(xq.z, W1[(ii+2)*FO+j], h[j]);
#pragma unroll
        for (int j = 0; j < FO; ++j) h[j] = fmaf(xq.w, W1[(ii+3)*FO+j], h[j]);
    }
#pragma unroll
    for (int j = 0; j < FO; ++j) h[j] = fmaxf(h[j], 0.f);

    float o[FO];
#pragma unroll
    for (int j = 0; j < FO; ++j) o[j] = b2[j];
#pragma unroll 1
    for (int i = 0; i < FO; ++i) {
        float hi = h[i];
#pragma unroll
        for (int j = 0; j < FO; ++j) o[j] = fmaf(hi, W2[i*FO+j], o[j]);
    }

    float* dst = x1p + (size_t)t * FP;
#pragma unroll
    for (int c = 0; c < 15; ++c) {
        float4 w;
        w.x = fmaxf(o[4*c+0], 0.f);
        w.y = fmaxf(o[4*c+1], 0.f);
        w.z = fmaxf(o[4*c+2], 0.f);
        w.w = fmaxf(o[4*c+3], 0.f);
        ((float4*)dst)[c] = w;
    }
    {
        float4 w;
        w.x = fmaxf(o[60], 0.f);
        w.y = fmaxf(o[61], 0.f);
        w.z = fmaxf(o[62], 0.f);
        w.w = 0.f;  // pad column stays zero
        ((float4*)dst)[15] = w;
    }
}

// ---------------- CSR build: histogram / scan / scatter ---------------------
__global__ __launch_bounds__(256) void k_hist(
    const int* __restrict__ rows, int* __restrict__ cnt, int nnz)
{
    int i = blockIdx.x * 256 + threadIdx.x;
    int stride = gridDim.x * 256;
    for (; i < nnz; i += stride) atomicAdd(&cnt[rows[i]], 1);
}

// in-place exclusive scan of 65536 ints: 1024 threads x 64 bins each
__global__ __launch_bounds__(1024) void k_scan(int* __restrict__ ptr)
{
    __shared__ int tot[1024];
    int t = threadIdx.x;
    int4* p4 = (int4*)(ptr + t * 64);
    int sum = 0;
#pragma unroll 1
    for (int q = 0; q < 16; ++q) {
        int4 b = p4[q];
        sum += b.x + b.y + b.z + b.w;
    }
    tot[t] = sum;
    __syncthreads();
#pragma unroll 1
    for (int off = 1; off < 1024; off <<= 1) {
        int v2 = 0;
        if (t >= off) v2 = tot[t - off];
        __syncthreads();
        if (t >= off) tot[t] += v2;
        __syncthreads();
    }
    int off = (t == 0) ? 0 : tot[t - 1];
#pragma unroll 1
    for (int q = 0; q < 16; ++q) {
        int4 b = p4[q];
        int4 w;
        w.x = off; off += b.x;
        w.y = off; off += b.y;
        w.z = off; off += b.z;
        w.w = off; off += b.w;
        p4[q] = w;
    }
}

__global__ __launch_bounds__(256) void k_scatter(
    const int* __restrict__ rows, const int* __restrict__ cols,
    const float* __restrict__ val, int* __restrict__ ptr,
    int* __restrict__ scol, float* __restrict__ sval, int nnz)
{
    int i = blockIdx.x * 256 + threadIdx.x;
    int stride = gridDim.x * 256;
    for (; i < nnz; i += stride) {
        int p = atomicAdd(&ptr[rows[i]], 1);
        scol[p] = cols[i];
        sval[p] = val[i];
    }
}

// ---------------- gather spmm: out[r] = sum val * xin[col], no atomics ------
// one wave per row, lane = feature (64, padded)
__global__ __launch_bounds__(256) void k_gather(
    const int* __restrict__ ptr, const int* __restrict__ scol,
    const float* __restrict__ sval, const float* __restrict__ xin,
    float* __restrict__ out, int n)
{
    int r = blockIdx.x * 4 + (threadIdx.x >> 6);
    int lane = threadIdx.x & 63;
    if (r >= n) return;
    int s = (r == 0) ? 0 : ptr[r - 1];
    int e = ptr[r];
    float acc = 0.f;
    int k = s;
#pragma unroll 1
    for (; k + 1 < e; k += 2) {
        int c0 = scol[k], c1 = scol[k + 1];
        float v0 = sval[k], v1 = sval[k + 1];
        float x0 = xin[((size_t)c0 << 6) + lane];
        float x1 = xin[((size_t)c1 << 6) + lane];
        acc = fmaf(v0, x0, acc);
        acc = fmaf(v1, x1, acc);
    }
    if (k < e) acc = fmaf(sval[k], xin[((size_t)scol[k] << 6) + lane], acc);
    out[((size_t)r << 6) + lane] = acc;
}

// ---------------- fallback spmm: COO scatter-atomic -------------------------
__global__ __launch_bounds__(256) void k_spmm(
    const int* __restrict__ rows, const int* __restrict__ cols,
    const float* __restrict__ val, const float* __restrict__ xin,
    float* __restrict__ acc, int nnz)
{
    int wave = blockIdx.x * 4 + (threadIdx.x >> 6);
    int lane = threadIdx.x & 63;
    int e0 = wave * NZPW;
#pragma unroll 1
    for (int k = 0; k < NZPW; ++k) {
        int e = e0 + k;
        if (e >= nnz) break;
        int r = rows[e];
        int c = cols[e];
        float v = val[e];
        float xv = xin[((size_t)c << 6) + lane];
        unsafeAtomicAdd(&acc[((size_t)r << 6) + lane], v * xv);
    }
}

// ------- combine: recompute self-MLP, add spmm2 result, classifier dot ------
__global__ __launch_bounds__(256) void k_combine(
    const float* __restrict__ x,
    const float* __restrict__ W1, const float* __restrict__ b1,
    const float* __restrict__ W2, const float* __restrict__ b2,
    const float* __restrict__ Wc, const float* __restrict__ bcp,
    const float* __restrict__ x2b,
    float* __restrict__ out, float* __restrict__ x3, int n)
{
    int t = blockIdx.x * 256 + threadIdx.x;
    if (t >= n) return;
    const float* xr = x + (size_t)t * FI;

    float h[FO];
#pragma unroll
    for (int j = 0; j < FO; ++j) h[j] = b1[j];
#pragma unroll 1
    for (int ii = 0; ii < FI; ii += 4) {
        float4 xq = *(const float4*)(xr + ii);
#pragma unroll
        for (int j = 0; j < FO; ++j) h[j] = fmaf(xq.x, W1[(ii+0)*FO+j], h[j]);
#pragma unroll
        for (int j = 0; j < FO; ++j) h[j] = fmaf(xq.y, W1[(ii+1)*FO+j], h[j]);
#pragma unroll
        for (int j = 0; j < FO; ++j) h[j] = fmaf(xq.z, W1[(ii+2)*FO+j], h[j]);
#pragma unroll
        for (int j = 0; j < FO; ++j) h[j] = fmaf(xq.w, W1[(ii+3)*FO+j], h[j]);
    }
#pragma unroll
    for (int j = 0; j < FO; ++j) h[j] = fmaxf(h[j], 0.f);

    float o[FO];
#pragma unroll
    for (int j = 0; j < FO; ++j) o[j] = b2[j];
#pragma unroll 1
    for (int i = 0; i < FO; ++i) {
        float hi = h[i];
#pragma unroll
        for (int j = 0; j < FO; ++j) o[j] = fmaf(hi, W2[i*FO+j], o[j]);
    }

    const float4* q4 = (const float4*)(x2b + (size_t)t * FP);
    float4* dst = (float4*)(out + (size_t)t * FP);
    float dot = 0.f;
#pragma unroll
    for (int c = 0; c < 15; ++c) {
        float4 q = q4[c];
        float4 w;
        w.x = q.x + fmaxf(o[4*c+0], 0.f);
        w.y = q.y + fmaxf(o[4*c+1], 0.f);
        w.z = q.z + fmaxf(o[4*c+2], 0.f);
        w.w = q.w + fmaxf(o[4*c+3], 0.f);
        dot = fmaf(w.x, Wc[4*c+0], dot);
        dot = fmaf(w.y, Wc[4*c+1], dot);
        dot = fmaf(w.z, Wc[4*c+2], dot);
        dot = fmaf(w.w, Wc[4*c+3], dot);
        dst[c] = w;
    }
    {
        float4 q = q4[15];
        float4 w;
        w.x = q.x + fmaxf(o[60], 0.f);
        w.y = q.y + fmaxf(o[61], 0.f);
        w.z = q.z + fmaxf(o[62], 0.f);
        w.w = 0.f;  // slot for sinkhorn channel (overwritten later)
        dot = fmaf(w.x, Wc[60], dot);
        dot = fmaf(w.y, Wc[61], dot);
        dot = fmaf(w.z, Wc[62], dot);
        dst[15] = w;
    }
    x3[t] = dot + bcp[0];
}

// ---------------- sinkhorn v2: 256x256, 20 iters, single block --------------
// exp2-domain (exp2f/log2f lower to v_exp_f32/v_log_f32 natively on gfx950);
// tile in regs (no spill: waves_per_eu(4,4) -> 128 VGPR budget);
// parallel per-line reductions: 4 threads/line, local 8 + 2x shfl_xor.
// X[a][b] = x3[a*256+b]; even iters LSE over a (per b), odd over b (per a).
__global__ __attribute__((amdgpu_waves_per_eu(4, 4))) __launch_bounds__(1024)
void k_sinkhorn(const float* __restrict__ x3, float* __restrict__ out)
{
    __shared__ float pm[32][258];   // partial max [tile][line]
    __shared__ float ps[32][258];   // partial sum [tile][line]
    __shared__ float ml[256];       // per-line max
    __shared__ float ll[256];       // per-line lse (log2 units)
    int tid = threadIdx.x;
    int ta = tid >> 5, tb = tid & 31;     // data tile coords
    int line4 = tid >> 2, sub = tid & 3;  // reduce coords: 4 threads/line

    float v[8][8];
#pragma unroll
    for (int i = 0; i < 8; ++i) {
        const float4* src = (const float4*)(x3 + (ta*8 + i)*256 + tb*8);
        float4 a0 = src[0], a1 = src[1];
        const float sc = INV_TAU * LOG2E;
        v[i][0] = a0.x * sc; v[i][1] = a0.y * sc;
        v[i][2] = a0.z * sc; v[i][3] = a0.w * sc;
        v[i][4] = a1.x * sc; v[i][5] = a1.y * sc;
        v[i][6] = a1.z * sc; v[i][7] = a1.w * sc;
    }

    // initial column-max partials (iter 0 normalizes over a, lines = columns b)
#pragma unroll
    for (int j = 0; j < 8; ++j) {
        float m = v[0][j];
#pragma unroll
        for (int i = 1; i < 8; ++i) m = fmaxf(m, v[i][j]);
        pm[ta][tb*8 + j] = m;
    }
    __syncthreads();

#pragma unroll 1
    for (int it = 0; it < 20; ++it) {
        bool even = (it & 1) == 0;
        // --- reduce line max (4 threads per line) ---
        {
            float M = -3.0e38f;
#pragma unroll
            for (int k = 0; k < 8; ++k) M = fmaxf(M, pm[sub*8 + k][line4]);
            M = fmaxf(M, __shfl_xor(M, 1));
            M = fmaxf(M, __shfl_xor(M, 2));
            if (sub == 0) ml[line4] = M;
        }
        __syncthreads();
        // --- per-thread partial sums of 2^(v-m) ---
        if (even) {
#pragma unroll
            for (int j = 0; j < 8; ++j) {
                float m = ml[tb*8 + j];
                float s = 0.f;
#pragma unroll
                for (int i = 0; i < 8; ++i) s += exp2f(v[i][j] - m);
                ps[ta][tb*8 + j] = s;
            }
        } else {
#pragma unroll
            for (int i = 0; i < 8; ++i) {
                float m = ml[ta*8 + i];
                float s = 0.f;
#pragma unroll
                for (int j = 0; j < 8; ++j) s += exp2f(v[i][j] - m);
                ps[tb][ta*8 + i] = s;
            }
        }
        __syncthreads();
        // --- reduce line sum -> lse ---
        {
            float S = 0.f;
#pragma unroll
            for (int k = 0; k < 8; ++k) S += ps[sub*8 + k][line4];
            S += __shfl_xor(S, 1);
            S += __shfl_xor(S, 2);
            if (sub == 0) ll[line4] = ml[line4] + log2f(S);
        }
        __syncthreads();
        // --- subtract lse; piggyback next-axis partial max ---
        if (even) {
            float l[8];
#pragma unroll
            for (int j = 0; j < 8; ++j) l[j] = ll[tb*8 + j];
#pragma unroll
            for (int i = 0; i < 8; ++i) {
                float m = -3.0e38f;
#pragma unroll
                for (int j = 0; j < 8; ++j) {
                    v[i][j] -= l[j];
                    m = fmaxf(m, v[i][j]);
                }
                pm[tb][ta*8 + i] = m;   // next axis: rows a
            }
        } else {
            float l[8];
#pragma unroll
            for (int i = 0; i < 8; ++i) l[i] = ll[ta*8 + i];
#pragma unroll
            for (int j = 0; j < 8; ++j) {
                float m = -3.0e38f;
#pragma unroll
                for (int i = 0; i < 8; ++i) {
                    v[i][j] -= l[i];
                    m = fmaxf(m, v[i][j]);
                }
                pm[ta][tb*8 + j] = m;   // next axis: columns b
            }
        }
        __syncthreads();
    }

#pragma unroll
    for (int i = 0; i < 8; ++i) {
        int a = ta*8 + i;
#pragma unroll
        for (int j = 0; j < 8; ++j) {
            out[((size_t)(a*256 + tb*8 + j) << 6) + 63] = exp2f(v[i][j]);
        }
    }
}

extern "C" void kernel_launch(void* const* d_in, const int* in_sizes, int n_in,
                              void* d_out, int out_size, void* d_ws, size_t ws_size,
                              hipStream_t stream)
{
    const float* K_value = (const float*)d_in[0];
    const int*   K_index = (const int*)d_in[1];
    const float* A_value = (const float*)d_in[2];
    const int*   A_index = (const int*)d_in[3];
    const float* x   = (const float*)d_in[4];
    const float* Wn1 = (const float*)d_in[5];
    const float* bn1 = (const float*)d_in[6];
    const float* Wn2 = (const float*)d_in[7];
    const float* bn2 = (const float*)d_in[8];
    const float* Ws1 = (const float*)d_in[9];
    const float* bs1 = (const float*)d_in[10];
    const float* Ws2 = (const float*)d_in[11];
    const float* bs2 = (const float*)d_in[12];
    const float* Wc  = (const float*)d_in[13];
    const float* bc  = (const float*)d_in[14];

    int nnzK = in_sizes[0];
    int nnzA = in_sizes[2];
    int n    = in_sizes[4] / FI;   // 65536

    float* outf = (float*)d_out;
    char*  ws   = (char*)d_ws;
    float* bufA = (float*)ws;                        // 16MB: x1 (padded), later x2
    float* x3   = bufA + (size_t)n * FP;             // 256KB
    int*   ptr  = (int*)(x3 + n);                    // 256KB row pointers/cursors
    int*   scol = ptr + n;                           // 4MB sorted cols
    float* sval = (float*)(scol + nnzK);             // 4MB sorted vals
    size_t need = ((size_t)n * FP + n + n) * 4 + (size_t)nnzK * 8;

    // 1. n_func MLP -> bufA (x1, padded to 64)
    k_mlp_n<<<(n + 255) / 256, 256, 0, stream>>>(x, Wn1, bn1, Wn2, bn2, bufA, n);

    if (ws_size >= need && n == 65536) {
        // ---- CSR-gather path (no fp32 atomics) ----
        // K: build CSR, Wx(d_out) = K @ x1
        (void)hipMemsetAsync(ptr, 0, (size_t)n * 4, stream);
        k_hist<<<2048, 256, 0, stream>>>(K_index, ptr, nnzK);
        k_scan<<<1, 1024, 0, stream>>>(ptr);
        k_scatter<<<2048, 256, 0, stream>>>(K_index, K_index + nnzK, K_value,
                                            ptr, scol, sval, nnzK);
        k_gather<<<(n + 3) / 4, 256, 0, stream>>>(ptr, scol, sval, bufA, outf, n);
        // A: build CSR, x2(bufA) = A @ Wx
        (void)hipMemsetAsync(ptr, 0, (size_t)n * 4, stream);
        k_hist<<<2048, 256, 0, stream>>>(A_index, ptr, nnzA);
        k_scan<<<1, 1024, 0, stream>>>(ptr);
        k_scatter<<<2048, 256, 0, stream>>>(A_index, A_index + nnzA, A_value,
                                            ptr, scol, sval, nnzA);
        k_gather<<<(n + 3) / 4, 256, 0, stream>>>(ptr, scol, sval, outf, bufA, n);
    } else {
        // ---- fallback: atomic scatter path ----
        (void)hipMemsetAsync(outf, 0, (size_t)n * FP * 4, stream);
        int blocks1 = (nnzK + 4 * NZPW - 1) / (4 * NZPW);
        k_spmm<<<blocks1, 256, 0, stream>>>(K_index, K_index + nnzK, K_value,
                                            bufA, outf, nnzK);
        (void)hipMemsetAsync(bufA, 0, (size_t)n * FP * 4, stream);
        int blocks2 = (nnzA + 4 * NZPW - 1) / (4 * NZPW);
        k_spmm<<<blocks2, 256, 0, stream>>>(A_index, A_index + nnzA, A_value,
                                            outf, bufA, nnzA);
        // x2 lands in bufA either way
    }

    // combine: self-MLP + x2(bufA), write out[:, :63], classifier -> x3
    k_combine<<<(n + 255) / 256, 256, 0, stream>>>(x, Ws1, bs1, Ws2, bs2, Wc, bc,
                                                   bufA, outf, x3, n);
    // sinkhorn -> out[:, 63]
    k_sinkhorn<<<1, 1024, 0, stream>>>(x3, outf);
}

// Round 4
// 646.707 us; speedup vs baseline: 1.1535x; 1.0048x over previous
//
#include <hip/hip_runtime.h>
#include <hip/hip_bf16.h>

#define FI 64
#define FO 63
#define FP 64
#define NZPW 8
#define INV_TAU 20.0f
#define LOG2E 1.4426950408889634f

// ---------------- MLP (n_func): x (n,64) -> x1 padded (n,64) ----------------
__global__ __launch_bounds__(256) void k_mlp_n(
    const float* __restrict__ x,
    const float* __restrict__ W1, const float* __restrict__ b1,
    const float* __restrict__ W2, const float* __restrict__ b2,
    float* __restrict__ x1p, int n)
{
    int t = blockIdx.x * 256 + threadIdx.x;
    if (t >= n) return;
    const float* xr = x + (size_t)t * FI;

    float h[FO];
#pragma unroll
    for (int j = 0; j < FO; ++j) h[j] = b1[j];
#pragma unroll 1
    for (int ii = 0; ii < FI; ii += 4) {
        float4 xq = *(const float4*)(xr + ii);
#pragma unroll
        for (int j = 0; j < FO; ++j) h[j] = fmaf(xq.x, W1[(ii+0)*FO+j], h[j]);
#pragma unroll
        for (int j = 0; j < FO; ++j) h[j] = fmaf(xq.y, W1[(ii+1)*FO+j], h[j]);
#pragma unroll
        for (int j = 0; j < FO; ++j) h[j] = fmaf(xq.z, W1[(ii+2)*FO+j], h[j]);
#pragma unroll
        for (int j = 0; j < FO; ++j) h[j] = fmaf(xq.w, W1[(ii+3)*FO+j], h[j]);
    }
#pragma unroll
    for (int j = 0; j < FO; ++j) h[j] = fmaxf(h[j], 0.f);

    float o[FO];
#pragma unroll
    for (int j = 0; j < FO; ++j) o[j] = b2[j];
#pragma unroll 1
    for (int i = 0; i < FO; ++i) {
        float hi = h[i];
#pragma unroll
        for (int j = 0; j < FO; ++j) o[j] = fmaf(hi, W2[i*FO+j], o[j]);
    }

    float* dst = x1p + (size_t)t * FP;
#pragma unroll
    for (int c = 0; c < 15; ++c) {
        float4 w;
        w.x = fmaxf(o[4*c+0], 0.f);
        w.y = fmaxf(o[4*c+1], 0.f);
        w.z = fmaxf(o[4*c+2], 0.f);
        w.w = fmaxf(o[4*c+3], 0.f);
        ((float4*)dst)[c] = w;
    }
    {
        float4 w;
        w.x = fmaxf(o[60], 0.f);
        w.y = fmaxf(o[61], 0.f);
        w.z = fmaxf(o[62], 0.f);
        w.w = 0.f;  // pad column stays zero
        ((float4*)dst)[15] = w;
    }
}

// ---------------- CSR build: histogram / scan / scatter ---------------------
__global__ __launch_bounds__(256) void k_hist(
    const int* __restrict__ rows, int* __restrict__ cnt, int nnz)
{
    int i = blockIdx.x * 256 + threadIdx.x;
    int stride = gridDim.x * 256;
    for (; i < nnz; i += stride) atomicAdd(&cnt[rows[i]], 1);
}

// in-place exclusive scan of 65536 ints: 1024 threads x 64 bins each
__global__ __launch_bounds__(1024) void k_scan(int* __restrict__ ptr)
{
    __shared__ int tot[1024];
    int t = threadIdx.x;
    int4* p4 = (int4*)(ptr + t * 64);
    int sum = 0;
#pragma unroll 1
    for (int q = 0; q < 16; ++q) {
        int4 b = p4[q];
        sum += b.x + b.y + b.z + b.w;
    }
    tot[t] = sum;
    __syncthreads();
#pragma unroll 1
    for (int off = 1; off < 1024; off <<= 1) {
        int v2 = 0;
        if (t >= off) v2 = tot[t - off];
        __syncthreads();
        if (t >= off) tot[t] += v2;
        __syncthreads();
    }
    int off = (t == 0) ? 0 : tot[t - 1];
#pragma unroll 1
    for (int q = 0; q < 16; ++q) {
        int4 b = p4[q];
        int4 w;
        w.x = off; off += b.x;
        w.y = off; off += b.y;
        w.z = off; off += b.z;
        w.w = off; off += b.w;
        p4[q] = w;
    }
}

__global__ __launch_bounds__(256) void k_scatter(
    const int* __restrict__ rows, const int* __restrict__ cols,
    const float* __restrict__ val, int* __restrict__ ptr,
    int* __restrict__ scol, float* __restrict__ sval, int nnz)
{
    int i = blockIdx.x * 256 + threadIdx.x;
    int stride = gridDim.x * 256;
    for (; i < nnz; i += stride) {
        int p = atomicAdd(&ptr[rows[i]], 1);
        scol[p] = cols[i];
        sval[p] = val[i];
    }
}

// ---------------- gather spmm: out[r] = sum val * xin[col], no atomics ------
// one wave per row, lane = feature (64, padded)
__global__ __launch_bounds__(256) void k_gather(
    const int* __restrict__ ptr, const int* __restrict__ scol,
    const float* __restrict__ sval, const float* __restrict__ xin,
    float* __restrict__ out, int n)
{
    int r = blockIdx.x * 4 + (threadIdx.x >> 6);
    int lane = threadIdx.x & 63;
    if (r >= n) return;
    int s = (r == 0) ? 0 : ptr[r - 1];
    int e = ptr[r];
    float acc = 0.f;
    int k = s;
#pragma unroll 1
    for (; k + 1 < e; k += 2) {
        int c0 = scol[k], c1 = scol[k + 1];
        float v0 = sval[k], v1 = sval[k + 1];
        float x0 = xin[((size_t)c0 << 6) + lane];
        float x1 = xin[((size_t)c1 << 6) + lane];
        acc = fmaf(v0, x0, acc);
        acc = fmaf(v1, x1, acc);
    }
    if (k < e) acc = fmaf(sval[k], xin[((size_t)scol[k] << 6) + lane], acc);
    out[((size_t)r << 6) + lane] = acc;
}

// ---------------- fallback spmm: COO scatter-atomic -------------------------
__global__ __launch_bounds__(256) void k_spmm(
    const int* __restrict__ rows, const int* __restrict__ cols,
    const float* __restrict__ val, const float* __restrict__ xin,
    float* __restrict__ acc, int nnz)
{
    int wave = blockIdx.x * 4 + (threadIdx.x >> 6);
    int lane = threadIdx.x & 63;
    int e0 = wave * NZPW;
#pragma unroll 1
    for (int k = 0; k < NZPW; ++k) {
        int e = e0 + k;
        if (e >= nnz) break;
        int r = rows[e];
        int c = cols[e];
        float v = val[e];
        float xv = xin[((size_t)c << 6) + lane];
        unsafeAtomicAdd(&acc[((size_t)r << 6) + lane], v * xv);
    }
}

// ------- combine: recompute self-MLP, add spmm2 result, classifier dot ------
__global__ __launch_bounds__(256) void k_combine(
    const float* __restrict__ x,
    const float* __restrict__ W1, const float* __restrict__ b1,
    const float* __restrict__ W2, const float* __restrict__ b2,
    const float* __restrict__ Wc, const float* __restrict__ bcp,
    const float* __restrict__ x2b,
    float* __restrict__ out, float* __restrict__ x3, int n)
{
    int t = blockIdx.x * 256 + threadIdx.x;
    if (t >= n) return;
    const float* xr = x + (size_t)t * FI;

    float h[FO];
#pragma unroll
    for (int j = 0; j < FO; ++j) h[j] = b1[j];
#pragma unroll 1
    for (int ii = 0; ii < FI; ii += 4) {
        float4 xq = *(const float4*)(xr + ii);
#pragma unroll
        for (int j = 0; j < FO; ++j) h[j] = fmaf(xq.x, W1[(ii+0)*FO+j], h[j]);
#pragma unroll
        for (int j = 0; j < FO; ++j) h[j] = fmaf(xq.y, W1[(ii+1)*FO+j], h[j]);
#pragma unroll
        for (int j = 0; j < FO; ++j) h[j] = fmaf(xq.z, W1[(ii+2)*FO+j], h[j]);
#pragma unroll
        for (int j = 0; j < FO; ++j) h[j] = fmaf(xq.w, W1[(ii+3)*FO+j], h[j]);
    }
#pragma unroll
    for (int j = 0; j < FO; ++j) h[j] = fmaxf(h[j], 0.f);

    float o[FO];
#pragma unroll
    for (int j = 0; j < FO; ++j) o[j] = b2[j];
#pragma unroll 1
    for (int i = 0; i < FO; ++i) {
        float hi = h[i];
#pragma unroll
        for (int j = 0; j < FO; ++j) o[j] = fmaf(hi, W2[i*FO+j], o[j]);
    }

    const float4* q4 = (const float4*)(x2b + (size_t)t * FP);
    float4* dst = (float4*)(out + (size_t)t * FP);
    float dot = 0.f;
#pragma unroll
    for (int c = 0; c < 15; ++c) {
        float4 q = q4[c];
        float4 w;
        w.x = q.x + fmaxf(o[4*c+0], 0.f);
        w.y = q.y + fmaxf(o[4*c+1], 0.f);
        w.z = q.z + fmaxf(o[4*c+2], 0.f);
        w.w = q.w + fmaxf(o[4*c+3], 0.f);
        dot = fmaf(w.x, Wc[4*c+0], dot);
        dot = fmaf(w.y, Wc[4*c+1], dot);
        dot = fmaf(w.z, Wc[4*c+2], dot);
        dot = fmaf(w.w, Wc[4*c+3], dot);
        dst[c] = w;
    }
    {
        float4 q = q4[15];
        float4 w;
        w.x = q.x + fmaxf(o[60], 0.f);
        w.y = q.y + fmaxf(o[61], 0.f);
        w.z = q.z + fmaxf(o[62], 0.f);
        w.w = 0.f;  // slot for sinkhorn channel (overwritten later)
        dot = fmaf(w.x, Wc[60], dot);
        dot = fmaf(w.y, Wc[61], dot);
        dot = fmaf(w.z, Wc[62], dot);
        dst[15] = w;
    }
    x3[t] = dot + bcp[0];
}

// ---------------- sinkhorn v3: 256x256, 20 iters, single block --------------
// exp2-domain; tile fully register-resident.
// __launch_bounds__(1024, 4): 2nd arg = min waves per EU -> VGPR cap 128
// (16 waves/block / 4 SIMDs = 4/EU exactly; no occupancy loss, kills spills).
// parallel per-line reductions: 4 threads/line, local 8 + 2x shfl_xor.
// X[a][b] = x3[a*256+b]; even iters LSE over a (per b), odd over b (per a).
__global__ __launch_bounds__(1024, 4)
void k_sinkhorn(const float* __restrict__ x3, float* __restrict__ out)
{
    __shared__ float pm[32][258];   // partial max [tile][line]
    __shared__ float ps[32][258];   // partial sum [tile][line]
    __shared__ float ml[256];       // per-line max
    __shared__ float ll[256];       // per-line lse (log2 units)
    int tid = threadIdx.x;
    int ta = tid >> 5, tb = tid & 31;     // data tile coords
    int line4 = tid >> 2, sub = tid & 3;  // reduce coords: 4 threads/line

    float v[8][8];
#pragma unroll
    for (int i = 0; i < 8; ++i) {
        const float4* src = (const float4*)(x3 + (ta*8 + i)*256 + tb*8);
        float4 a0 = src[0], a1 = src[1];
        const float sc = INV_TAU * LOG2E;
        v[i][0] = a0.x * sc; v[i][1] = a0.y * sc;
        v[i][2] = a0.z * sc; v[i][3] = a0.w * sc;
        v[i][4] = a1.x * sc; v[i][5] = a1.y * sc;
        v[i][6] = a1.z * sc; v[i][7] = a1.w * sc;
    }

    // initial column-max partials (iter 0 normalizes over a, lines = columns b)
#pragma unroll
    for (int j = 0; j < 8; ++j) {
        float m = v[0][j];
#pragma unroll
        for (int i = 1; i < 8; ++i) m = fmaxf(m, v[i][j]);
        pm[ta][tb*8 + j] = m;
    }
    __syncthreads();

#pragma unroll 1
    for (int it = 0; it < 20; ++it) {
        bool even = (it & 1) == 0;
        // --- reduce line max (4 threads per line) ---
        {
            float M = -3.0e38f;
#pragma unroll
            for (int k = 0; k < 8; ++k) M = fmaxf(M, pm[sub*8 + k][line4]);
            M = fmaxf(M, __shfl_xor(M, 1));
            M = fmaxf(M, __shfl_xor(M, 2));
            if (sub == 0) ml[line4] = M;
        }
        __syncthreads();
        // --- per-thread partial sums of 2^(v-m) ---
        if (even) {
#pragma unroll
            for (int j = 0; j < 8; ++j) {
                float m = ml[tb*8 + j];
                float s = 0.f;
#pragma unroll
                for (int i = 0; i < 8; ++i) s += exp2f(v[i][j] - m);
                ps[ta][tb*8 + j] = s;
            }
        } else {
#pragma unroll
            for (int i = 0; i < 8; ++i) {
                float m = ml[ta*8 + i];
                float s = 0.f;
#pragma unroll
                for (int j = 0; j < 8; ++j) s += exp2f(v[i][j] - m);
                ps[tb][ta*8 + i] = s;
            }
        }
        __syncthreads();
        // --- reduce line sum -> lse ---
        {
            float S = 0.f;
#pragma unroll
            for (int k = 0; k < 8; ++k) S += ps[sub*8 + k][line4];
            S += __shfl_xor(S, 1);
            S += __shfl_xor(S, 2);
            if (sub == 0) ll[line4] = ml[line4] + log2f(S);
        }
        __syncthreads();
        // --- subtract lse; piggyback next-axis partial max ---
        if (even) {
            float l[8];
#pragma unroll
            for (int j = 0; j < 8; ++j) l[j] = ll[tb*8 + j];
#pragma unroll
            for (int i = 0; i < 8; ++i) {
                float m = -3.0e38f;
#pragma unroll
                for (int j = 0; j < 8; ++j) {
                    v[i][j] -= l[j];
                    m = fmaxf(m, v[i][j]);
                }
                pm[tb][ta*8 + i] = m;   // next axis: rows a
            }
        } else {
            float l[8];
#pragma unroll
            for (int i = 0; i < 8; ++i) l[i] = ll[ta*8 + i];
#pragma unroll
            for (int j = 0; j < 8; ++j) {
                float m = -3.0e38f;
#pragma unroll
                for (int i = 0; i < 8; ++i) {
                    v[i][j] -= l[i];
                    m = fmaxf(m, v[i][j]);
                }
                pm[ta][tb*8 + j] = m;   // next axis: columns b
            }
        }
        __syncthreads();
    }

#pragma unroll
    for (int i = 0; i < 8; ++i) {
        int a = ta*8 + i;
#pragma unroll
        for (int j = 0; j < 8; ++j) {
            out[((size_t)(a*256 + tb*8 + j) << 6) + 63] = exp2f(v[i][j]);
        }
    }
}

extern "C" void kernel_launch(void* const* d_in, const int* in_sizes, int n_in,
                              void* d_out, int out_size, void* d_ws, size_t ws_size,
                              hipStream_t stream)
{
    const float* K_value = (const float*)d_in[0];
    const int*   K_index = (const int*)d_in[1];
    const float* A_value = (const float*)d_in[2];
    const int*   A_index = (const int*)d_in[3];
    const float* x   = (const float*)d_in[4];
    const float* Wn1 = (const float*)d_in[5];
    const float* bn1 = (const float*)d_in[6];
    const float* Wn2 = (const float*)d_in[7];
    const float* bn2 = (const float*)d_in[8];
    const float* Ws1 = (const float*)d_in[9];
    const float* bs1 = (const float*)d_in[10];
    const float* Ws2 = (const float*)d_in[11];
    const float* bs2 = (const float*)d_in[12];
    const float* Wc  = (const float*)d_in[13];
    const float* bc  = (const float*)d_in[14];

    int nnzK = in_sizes[0];
    int nnzA = in_sizes[2];
    int n    = in_sizes[4] / FI;   // 65536

    float* outf = (float*)d_out;
    char*  ws   = (char*)d_ws;
    float* bufA = (float*)ws;                        // 16MB: x1 (padded), later x2
    float* x3   = bufA + (size_t)n * FP;             // 256KB
    int*   ptr  = (int*)(x3 + n);                    // 256KB row pointers/cursors
    int*   scol = ptr + n;                           // 4MB sorted cols
    float* sval = (float*)(scol + nnzK);             // 4MB sorted vals
    size_t need = ((size_t)n * FP + n + n) * 4 + (size_t)nnzK * 8;

    // 1. n_func MLP -> bufA (x1, padded to 64)
    k_mlp_n<<<(n + 255) / 256, 256, 0, stream>>>(x, Wn1, bn1, Wn2, bn2, bufA, n);

    if (ws_size >= need && n == 65536) {
        // ---- CSR-gather path (no fp32 atomics) ----
        // K: build CSR, Wx(d_out) = K @ x1
        (void)hipMemsetAsync(ptr, 0, (size_t)n * 4, stream);
        k_hist<<<2048, 256, 0, stream>>>(K_index, ptr, nnzK);
        k_scan<<<1, 1024, 0, stream>>>(ptr);
        k_scatter<<<2048, 256, 0, stream>>>(K_index, K_index + nnzK, K_value,
                                            ptr, scol, sval, nnzK);
        k_gather<<<(n + 3) / 4, 256, 0, stream>>>(ptr, scol, sval, bufA, outf, n);
        // A: build CSR, x2(bufA) = A @ Wx
        (void)hipMemsetAsync(ptr, 0, (size_t)n * 4, stream);
        k_hist<<<2048, 256, 0, stream>>>(A_index, ptr, nnzA);
        k_scan<<<1, 1024, 0, stream>>>(ptr);
        k_scatter<<<2048, 256, 0, stream>>>(A_index, A_index + nnzA, A_value,
                                            ptr, scol, sval, nnzA);
        k_gather<<<(n + 3) / 4, 256, 0, stream>>>(ptr, scol, sval, outf, bufA, n);
    } else {
        // ---- fallback: atomic scatter path ----
        (void)hipMemsetAsync(outf, 0, (size_t)n * FP * 4, stream);
        int blocks1 = (nnzK + 4 * NZPW - 1) / (4 * NZPW);
        k_spmm<<<blocks1, 256, 0, stream>>>(K_index, K_index + nnzK, K_value,
                                            bufA, outf, nnzK);
        (void)hipMemsetAsync(bufA, 0, (size_t)n * FP * 4, stream);
        int blocks2 = (nnzA + 4 * NZPW - 1) / (4 * NZPW);
        k_spmm<<<blocks2, 256, 0, stream>>>(A_index, A_index + nnzA, A_value,
                                            outf, bufA, nnzA);
        // x2 lands in bufA either way
    }

    // combine: self-MLP + x2(bufA), write out[:, :63], classifier -> x3
    k_combine<<<(n + 255) / 256, 256, 0, stream>>>(x, Ws1, bs1, Ws2, bs2, Wc, bc,
                                                   bufA, outf, x3, n);
    // sinkhorn -> out[:, 63]
    k_sinkhorn<<<1, 1024, 0, stream>>>(x3, outf);
}

// Round 5
// 603.290 us; speedup vs baseline: 1.2365x; 1.0720x over previous
//
#include <hip/hip_runtime.h>
#include <hip/hip_bf16.h>

#define FI 64
#define FO 63
#define FP 64
#define NZPW 8
#define INV_TAU 20.0f
#define LOG2E 1.4426950408889634f

// ---------------- MLP (n_func): x (n,64) -> x1 padded (n,64) ----------------
__global__ __launch_bounds__(256) void k_mlp_n(
    const float* __restrict__ x,
    const float* __restrict__ W1, const float* __restrict__ b1,
    const float* __restrict__ W2, const float* __restrict__ b2,
    float* __restrict__ x1p, int n)
{
    int t = blockIdx.x * 256 + threadIdx.x;
    if (t >= n) return;
    const float* xr = x + (size_t)t * FI;

    float h[FO];
#pragma unroll
    for (int j = 0; j < FO; ++j) h[j] = b1[j];
#pragma unroll 1
    for (int ii = 0; ii < FI; ii += 4) {
        float4 xq = *(const float4*)(xr + ii);
#pragma unroll
        for (int j = 0; j < FO; ++j) h[j] = fmaf(xq.x, W1[(ii+0)*FO+j], h[j]);
#pragma unroll
        for (int j = 0; j < FO; ++j) h[j] = fmaf(xq.y, W1[(ii+1)*FO+j], h[j]);
#pragma unroll
        for (int j = 0; j < FO; ++j) h[j] = fmaf(xq.z, W1[(ii+2)*FO+j], h[j]);
#pragma unroll
        for (int j = 0; j < FO; ++j) h[j] = fmaf(xq.w, W1[(ii+3)*FO+j], h[j]);
    }
#pragma unroll
    for (int j = 0; j < FO; ++j) h[j] = fmaxf(h[j], 0.f);

    float o[FO];
#pragma unroll
    for (int j = 0; j < FO; ++j) o[j] = b2[j];
#pragma unroll 1
    for (int i = 0; i < FO; ++i) {
        float hi = h[i];
#pragma unroll
        for (int j = 0; j < FO; ++j) o[j] = fmaf(hi, W2[i*FO+j], o[j]);
    }

    float* dst = x1p + (size_t)t * FP;
#pragma unroll
    for (int c = 0; c < 15; ++c) {
        float4 w;
        w.x = fmaxf(o[4*c+0], 0.f);
        w.y = fmaxf(o[4*c+1], 0.f);
        w.z = fmaxf(o[4*c+2], 0.f);
        w.w = fmaxf(o[4*c+3], 0.f);
        ((float4*)dst)[c] = w;
    }
    {
        float4 w;
        w.x = fmaxf(o[60], 0.f);
        w.y = fmaxf(o[61], 0.f);
        w.z = fmaxf(o[62], 0.f);
        w.w = 0.f;  // pad column stays zero
        ((float4*)dst)[15] = w;
    }
}

// ---------------- CSR build: histogram / scan / scatter ---------------------
__global__ __launch_bounds__(256) void k_hist(
    const int* __restrict__ rows, int* __restrict__ cnt, int nnz)
{
    int i = blockIdx.x * 256 + threadIdx.x;
    int stride = gridDim.x * 256;
    for (; i < nnz; i += stride) atomicAdd(&cnt[rows[i]], 1);
}

// in-place exclusive scan of 65536 ints: 1024 threads x 64 bins each
__global__ __launch_bounds__(1024) void k_scan(int* __restrict__ ptr)
{
    __shared__ int tot[1024];
    int t = threadIdx.x;
    int4* p4 = (int4*)(ptr + t * 64);
    int sum = 0;
#pragma unroll 1
    for (int q = 0; q < 16; ++q) {
        int4 b = p4[q];
        sum += b.x + b.y + b.z + b.w;
    }
    tot[t] = sum;
    __syncthreads();
#pragma unroll 1
    for (int off = 1; off < 1024; off <<= 1) {
        int v2 = 0;
        if (t >= off) v2 = tot[t - off];
        __syncthreads();
        if (t >= off) tot[t] += v2;
        __syncthreads();
    }
    int off = (t == 0) ? 0 : tot[t - 1];
#pragma unroll 1
    for (int q = 0; q < 16; ++q) {
        int4 b = p4[q];
        int4 w;
        w.x = off; off += b.x;
        w.y = off; off += b.y;
        w.z = off; off += b.z;
        w.w = off; off += b.w;
        p4[q] = w;
    }
}

__global__ __launch_bounds__(256) void k_scatter(
    const int* __restrict__ rows, const int* __restrict__ cols,
    const float* __restrict__ val, int* __restrict__ ptr,
    int* __restrict__ scol, float* __restrict__ sval, int nnz)
{
    int i = blockIdx.x * 256 + threadIdx.x;
    int stride = gridDim.x * 256;
    for (; i < nnz; i += stride) {
        int p = atomicAdd(&ptr[rows[i]], 1);
        scol[p] = cols[i];
        sval[p] = val[i];
    }
}

// ---------------- gather spmm: out[r] = sum val * xin[col], no atomics ------
// one wave per row, lane = feature (64, padded)
__global__ __launch_bounds__(256) void k_gather(
    const int* __restrict__ ptr, const int* __restrict__ scol,
    const float* __restrict__ sval, const float* __restrict__ xin,
    float* __restrict__ out, int n)
{
    int r = blockIdx.x * 4 + (threadIdx.x >> 6);
    int lane = threadIdx.x & 63;
    if (r >= n) return;
    int s = (r == 0) ? 0 : ptr[r - 1];
    int e = ptr[r];
    float acc = 0.f;
    int k = s;
#pragma unroll 1
    for (; k + 1 < e; k += 2) {
        int c0 = scol[k], c1 = scol[k + 1];
        float v0 = sval[k], v1 = sval[k + 1];
        float x0 = xin[((size_t)c0 << 6) + lane];
        float x1 = xin[((size_t)c1 << 6) + lane];
        acc = fmaf(v0, x0, acc);
        acc = fmaf(v1, x1, acc);
    }
    if (k < e) acc = fmaf(sval[k], xin[((size_t)scol[k] << 6) + lane], acc);
    out[((size_t)r << 6) + lane] = acc;
}

// ---------------- fallback spmm: COO scatter-atomic -------------------------
__global__ __launch_bounds__(256) void k_spmm(
    const int* __restrict__ rows, const int* __restrict__ cols,
    const float* __restrict__ val, const float* __restrict__ xin,
    float* __restrict__ acc, int nnz)
{
    int wave = blockIdx.x * 4 + (threadIdx.x >> 6);
    int lane = threadIdx.x & 63;
    int e0 = wave * NZPW;
#pragma unroll 1
    for (int k = 0; k < NZPW; ++k) {
        int e = e0 + k;
        if (e >= nnz) break;
        int r = rows[e];
        int c = cols[e];
        float v = val[e];
        float xv = xin[((size_t)c << 6) + lane];
        unsafeAtomicAdd(&acc[((size_t)r << 6) + lane], v * xv);
    }
}

// ------- combine: recompute self-MLP, add spmm2 result, classifier dot ------
__global__ __launch_bounds__(256) void k_combine(
    const float* __restrict__ x,
    const float* __restrict__ W1, const float* __restrict__ b1,
    const float* __restrict__ W2, const float* __restrict__ b2,
    const float* __restrict__ Wc, const float* __restrict__ bcp,
    const float* __restrict__ x2b,
    float* __restrict__ out, float* __restrict__ x3, int n)
{
    int t = blockIdx.x * 256 + threadIdx.x;
    if (t >= n) return;
    const float* xr = x + (size_t)t * FI;

    float h[FO];
#pragma unroll
    for (int j = 0; j < FO; ++j) h[j] = b1[j];
#pragma unroll 1
    for (int ii = 0; ii < FI; ii += 4) {
        float4 xq = *(const float4*)(xr + ii);
#pragma unroll
        for (int j = 0; j < FO; ++j) h[j] = fmaf(xq.x, W1[(ii+0)*FO+j], h[j]);
#pragma unroll
        for (int j = 0; j < FO; ++j) h[j] = fmaf(xq.y, W1[(ii+1)*FO+j], h[j]);
#pragma unroll
        for (int j = 0; j < FO; ++j) h[j] = fmaf(xq.z, W1[(ii+2)*FO+j], h[j]);
#pragma unroll
        for (int j = 0; j < FO; ++j) h[j] = fmaf(xq.w, W1[(ii+3)*FO+j], h[j]);
    }
#pragma unroll
    for (int j = 0; j < FO; ++j) h[j] = fmaxf(h[j], 0.f);

    float o[FO];
#pragma unroll
    for (int j = 0; j < FO; ++j) o[j] = b2[j];
#pragma unroll 1
    for (int i = 0; i < FO; ++i) {
        float hi = h[i];
#pragma unroll
        for (int j = 0; j < FO; ++j) o[j] = fmaf(hi, W2[i*FO+j], o[j]);
    }

    const float4* q4 = (const float4*)(x2b + (size_t)t * FP);
    float4* dst = (float4*)(out + (size_t)t * FP);
    float dot = 0.f;
#pragma unroll
    for (int c = 0; c < 15; ++c) {
        float4 q = q4[c];
        float4 w;
        w.x = q.x + fmaxf(o[4*c+0], 0.f);
        w.y = q.y + fmaxf(o[4*c+1], 0.f);
        w.z = q.z + fmaxf(o[4*c+2], 0.f);
        w.w = q.w + fmaxf(o[4*c+3], 0.f);
        dot = fmaf(w.x, Wc[4*c+0], dot);
        dot = fmaf(w.y, Wc[4*c+1], dot);
        dot = fmaf(w.z, Wc[4*c+2], dot);
        dot = fmaf(w.w, Wc[4*c+3], dot);
        dst[c] = w;
    }
    {
        float4 q = q4[15];
        float4 w;
        w.x = q.x + fmaxf(o[60], 0.f);
        w.y = q.y + fmaxf(o[61], 0.f);
        w.z = q.z + fmaxf(o[62], 0.f);
        w.w = 0.f;  // slot for sinkhorn channel (overwritten later)
        dot = fmaf(w.x, Wc[60], dot);
        dot = fmaf(w.y, Wc[61], dot);
        dot = fmaf(w.z, Wc[62], dot);
        dst[15] = w;
    }
    x3[t] = dot + bcp[0];
}

// ---------------- sinkhorn v4: scalar-offset formulation --------------------
// log_s(it) = u - R[a] - C[b]: the 64K-element tile u is READ-ONLY; only the
// 256-float line offsets R,C (LDS) evolve. Per iter: one fused online-(m,s)
// pass (chunk max+sum -> LDS -> 4-thread tree merge -> scalar update).
// After the first normalization all relevant terms are <=0, so per-line max
// tracking keeps everything finite (chunk max subtracted before exp2).
// LDS deliberately >80KB: one block/CU -> backend register budget 4 waves/EU
// = 128 VGPR, enough for u[8][8]+temps (~90) with no scratch spill.
__global__ __launch_bounds__(1024) __attribute__((amdgpu_waves_per_eu(4, 4)))
void k_sinkhorn(const float* __restrict__ x3, float* __restrict__ out)
{
    __shared__ float pm[256][41];   // [line][chunk] partial max (41: pad + LDS sizing)
    __shared__ float ps[256][41];   // [line][chunk] partial sum
    __shared__ float Rl[256];       // row offsets (index a)
    __shared__ float Cl[256];       // col offsets (index b)
    const int tid = threadIdx.x;
    const int ta = tid >> 5, tb = tid & 31;     // tile coords
    const int line4 = tid >> 2, sub = tid & 3;  // merge coords: 4 threads/line

    float u[8][8];
#pragma unroll
    for (int i = 0; i < 8; ++i) {
        const float4* src = (const float4*)(x3 + (ta*8 + i)*256 + tb*8);
        float4 a0 = src[0], a1 = src[1];
        const float sc = INV_TAU * LOG2E;
        u[i][0] = a0.x * sc; u[i][1] = a0.y * sc;
        u[i][2] = a0.z * sc; u[i][3] = a0.w * sc;
        u[i][4] = a1.x * sc; u[i][5] = a1.y * sc;
        u[i][6] = a1.z * sc; u[i][7] = a1.w * sc;
    }
    if (tid < 256) { Rl[tid] = 0.f; Cl[tid] = 0.f; }
    __syncthreads();

#pragma unroll 1
    for (int it = 0; it < 20; ++it) {
        const bool even = (it & 1) == 0;
        if (even) {
            // lines = columns b; LSE over a of (u - R[a]) -> new C[b]
            float r[8];
#pragma unroll
            for (int i = 0; i < 8; ++i) r[i] = Rl[ta*8 + i];
#pragma unroll
            for (int j = 0; j < 8; ++j) {
                float m = u[0][j] - r[0];
#pragma unroll
                for (int i = 1; i < 8; ++i) m = fmaxf(m, u[i][j] - r[i]);
                float s = 0.f;
#pragma unroll
                for (int i = 0; i < 8; ++i) s += exp2f(u[i][j] - r[i] - m);
                pm[tb*8 + j][ta] = m;
                ps[tb*8 + j][ta] = s;
            }
        } else {
            // lines = rows a; LSE over b of (u - C[b]) -> new R[a]
            float c[8];
#pragma unroll
            for (int j = 0; j < 8; ++j) c[j] = Cl[tb*8 + j];
#pragma unroll
            for (int i = 0; i < 8; ++i) {
                float m = u[i][0] - c[0];
#pragma unroll
                for (int j = 1; j < 8; ++j) m = fmaxf(m, u[i][j] - c[j]);
                float s = 0.f;
#pragma unroll
                for (int j = 0; j < 8; ++j) s += exp2f(u[i][j] - c[j] - m);
                pm[ta*8 + i][tb] = m;
                ps[ta*8 + i][tb] = s;
            }
        }
        __syncthreads();
        // merge 32 chunks per line: 8 serial + 2 shfl (lanes sub^1, sub^2)
        float M = pm[line4][sub*8];
        float S = ps[line4][sub*8];
#pragma unroll
        for (int k = 1; k < 8; ++k) {
            float m2 = pm[line4][sub*8 + k];
            float s2 = ps[line4][sub*8 + k];
            float nm = fmaxf(M, m2);
            S = S * exp2f(M - nm) + s2 * exp2f(m2 - nm);
            M = nm;
        }
#pragma unroll
        for (int d = 1; d <= 2; d <<= 1) {
            float m2 = __shfl_xor(M, d);
            float s2 = __shfl_xor(S, d);
            float nm = fmaxf(M, m2);
            S = S * exp2f(M - nm) + s2 * exp2f(m2 - nm);
            M = nm;
        }
        if (sub == 0) {
            float l = M + log2f(S);
            if (even) Cl[line4] = l; else Rl[line4] = l;
        }
        __syncthreads();
    }

    float r[8], c[8];
#pragma unroll
    for (int i = 0; i < 8; ++i) r[i] = Rl[ta*8 + i];
#pragma unroll
    for (int j = 0; j < 8; ++j) c[j] = Cl[tb*8 + j];
#pragma unroll
    for (int i = 0; i < 8; ++i) {
        int a = ta*8 + i;
#pragma unroll
        for (int j = 0; j < 8; ++j) {
            out[((size_t)(a*256 + tb*8 + j) << 6) + 63] =
                exp2f(u[i][j] - r[i] - c[j]);
        }
    }
}

extern "C" void kernel_launch(void* const* d_in, const int* in_sizes, int n_in,
                              void* d_out, int out_size, void* d_ws, size_t ws_size,
                              hipStream_t stream)
{
    const float* K_value = (const float*)d_in[0];
    const int*   K_index = (const int*)d_in[1];
    const float* A_value = (const float*)d_in[2];
    const int*   A_index = (const int*)d_in[3];
    const float* x   = (const float*)d_in[4];
    const float* Wn1 = (const float*)d_in[5];
    const float* bn1 = (const float*)d_in[6];
    const float* Wn2 = (const float*)d_in[7];
    const float* bn2 = (const float*)d_in[8];
    const float* Ws1 = (const float*)d_in[9];
    const float* bs1 = (const float*)d_in[10];
    const float* Ws2 = (const float*)d_in[11];
    const float* bs2 = (const float*)d_in[12];
    const float* Wc  = (const float*)d_in[13];
    const float* bc  = (const float*)d_in[14];

    int nnzK = in_sizes[0];
    int nnzA = in_sizes[2];
    int n    = in_sizes[4] / FI;   // 65536

    float* outf = (float*)d_out;
    char*  ws   = (char*)d_ws;
    float* bufA = (float*)ws;                        // 16MB: x1 (padded), later x2
    float* x3   = bufA + (size_t)n * FP;             // 256KB
    int*   ptr  = (int*)(x3 + n);                    // 256KB row pointers/cursors
    int*   scol = ptr + n;                           // 4MB sorted cols
    float* sval = (float*)(scol + nnzK);             // 4MB sorted vals
    size_t need = ((size_t)n * FP + n + n) * 4 + (size_t)nnzK * 8;

    // 1. n_func MLP -> bufA (x1, padded to 64)
    k_mlp_n<<<(n + 255) / 256, 256, 0, stream>>>(x, Wn1, bn1, Wn2, bn2, bufA, n);

    if (ws_size >= need && n == 65536) {
        // ---- CSR-gather path (no fp32 atomics) ----
        // K: build CSR, Wx(d_out) = K @ x1
        (void)hipMemsetAsync(ptr, 0, (size_t)n * 4, stream);
        k_hist<<<2048, 256, 0, stream>>>(K_index, ptr, nnzK);
        k_scan<<<1, 1024, 0, stream>>>(ptr);
        k_scatter<<<2048, 256, 0, stream>>>(K_index, K_index + nnzK, K_value,
                                            ptr, scol, sval, nnzK);
        k_gather<<<(n + 3) / 4, 256, 0, stream>>>(ptr, scol, sval, bufA, outf, n);
        // A: build CSR, x2(bufA) = A @ Wx
        (void)hipMemsetAsync(ptr, 0, (size_t)n * 4, stream);
        k_hist<<<2048, 256, 0, stream>>>(A_index, ptr, nnzA);
        k_scan<<<1, 1024, 0, stream>>>(ptr);
        k_scatter<<<2048, 256, 0, stream>>>(A_index, A_index + nnzA, A_value,
                                            ptr, scol, sval, nnzA);
        k_gather<<<(n + 3) / 4, 256, 0, stream>>>(ptr, scol, sval, outf, bufA, n);
    } else {
        // ---- fallback: atomic scatter path ----
        (void)hipMemsetAsync(outf, 0, (size_t)n * FP * 4, stream);
        int blocks1 = (nnzK + 4 * NZPW - 1) / (4 * NZPW);
        k_spmm<<<blocks1, 256, 0, stream>>>(K_index, K_index + nnzK, K_value,
                                            bufA, outf, nnzK);
        (void)hipMemsetAsync(bufA, 0, (size_t)n * FP * 4, stream);
        int blocks2 = (nnzA + 4 * NZPW - 1) / (4 * NZPW);
        k_spmm<<<blocks2, 256, 0, stream>>>(A_index, A_index + nnzA, A_value,
                                            outf, bufA, nnzA);
        // x2 lands in bufA either way
    }

    // combine: self-MLP + x2(bufA), write out[:, :63], classifier -> x3
    k_combine<<<(n + 255) / 256, 256, 0, stream>>>(x, Ws1, bs1, Ws2, bs2, Wc, bc,
                                                   bufA, outf, x3, n);
    // sinkhorn -> out[:, 63]
    k_sinkhorn<<<1, 1024, 0, stream>>>(x3, outf);
}

// Round 6
// 596.084 us; speedup vs baseline: 1.2515x; 1.0121x over previous
//
#include <hip/hip_runtime.h>
#include <hip/hip_bf16.h>

#define FI 64
#define FO 63
#define FP 64
#define NZPW 8
#define INV_TAU 20.0f
#define LOG2E 1.4426950408889634f

// ---------------- MLP (n_func): x (n,64) -> x1 padded (n,64) ----------------
__global__ __launch_bounds__(256) void k_mlp_n(
    const float* __restrict__ x,
    const float* __restrict__ W1, const float* __restrict__ b1,
    const float* __restrict__ W2, const float* __restrict__ b2,
    float* __restrict__ x1p, int n)
{
    int t = blockIdx.x * 256 + threadIdx.x;
    if (t >= n) return;
    const float* xr = x + (size_t)t * FI;

    float h[FO];
#pragma unroll
    for (int j = 0; j < FO; ++j) h[j] = b1[j];
#pragma unroll 1
    for (int ii = 0; ii < FI; ii += 4) {
        float4 xq = *(const float4*)(xr + ii);
#pragma unroll
        for (int j = 0; j < FO; ++j) h[j] = fmaf(xq.x, W1[(ii+0)*FO+j], h[j]);
#pragma unroll
        for (int j = 0; j < FO; ++j) h[j] = fmaf(xq.y, W1[(ii+1)*FO+j], h[j]);
#pragma unroll
        for (int j = 0; j < FO; ++j) h[j] = fmaf(xq.z, W1[(ii+2)*FO+j], h[j]);
#pragma unroll
        for (int j = 0; j < FO; ++j) h[j] = fmaf(xq.w, W1[(ii+3)*FO+j], h[j]);
    }
#pragma unroll
    for (int j = 0; j < FO; ++j) h[j] = fmaxf(h[j], 0.f);

    float o[FO];
#pragma unroll
    for (int j = 0; j < FO; ++j) o[j] = b2[j];
#pragma unroll 1
    for (int i = 0; i < FO; ++i) {
        float hi = h[i];
#pragma unroll
        for (int j = 0; j < FO; ++j) o[j] = fmaf(hi, W2[i*FO+j], o[j]);
    }

    float* dst = x1p + (size_t)t * FP;
#pragma unroll
    for (int c = 0; c < 15; ++c) {
        float4 w;
        w.x = fmaxf(o[4*c+0], 0.f);
        w.y = fmaxf(o[4*c+1], 0.f);
        w.z = fmaxf(o[4*c+2], 0.f);
        w.w = fmaxf(o[4*c+3], 0.f);
        ((float4*)dst)[c] = w;
    }
    {
        float4 w;
        w.x = fmaxf(o[60], 0.f);
        w.y = fmaxf(o[61], 0.f);
        w.z = fmaxf(o[62], 0.f);
        w.w = 0.f;  // pad column stays zero
        ((float4*)dst)[15] = w;
    }
}

// ---------------- CSR build: histogram / scan / scatter ---------------------
__global__ __launch_bounds__(256) void k_hist(
    const int* __restrict__ rows, int* __restrict__ cnt, int nnz)
{
    int i = blockIdx.x * 256 + threadIdx.x;
    int stride = gridDim.x * 256;
    for (; i < nnz; i += stride) atomicAdd(&cnt[rows[i]], 1);
}

// in-place exclusive scan of 65536 ints: 1024 threads x 64 bins each
__global__ __launch_bounds__(1024) void k_scan(int* __restrict__ ptr)
{
    __shared__ int tot[1024];
    int t = threadIdx.x;
    int4* p4 = (int4*)(ptr + t * 64);
    int sum = 0;
#pragma unroll 1
    for (int q = 0; q < 16; ++q) {
        int4 b = p4[q];
        sum += b.x + b.y + b.z + b.w;
    }
    tot[t] = sum;
    __syncthreads();
#pragma unroll 1
    for (int off = 1; off < 1024; off <<= 1) {
        int v2 = 0;
        if (t >= off) v2 = tot[t - off];
        __syncthreads();
        if (t >= off) tot[t] += v2;
        __syncthreads();
    }
    int off = (t == 0) ? 0 : tot[t - 1];
#pragma unroll 1
    for (int q = 0; q < 16; ++q) {
        int4 b = p4[q];
        int4 w;
        w.x = off; off += b.x;
        w.y = off; off += b.y;
        w.z = off; off += b.z;
        w.w = off; off += b.w;
        p4[q] = w;
    }
}

// packed scatter: one 8B store per entry (col, val) instead of two 4B stores
__global__ __launch_bounds__(256) void k_scatter(
    const int* __restrict__ rows, const int* __restrict__ cols,
    const float* __restrict__ val, int* __restrict__ ptr,
    int2* __restrict__ sdat, int nnz)
{
    int i = blockIdx.x * 256 + threadIdx.x;
    int stride = gridDim.x * 256;
    for (; i < nnz; i += stride) {
        int p = atomicAdd(&ptr[rows[i]], 1);
        sdat[p] = make_int2(cols[i], __float_as_int(val[i]));
    }
}

// ---------------- gather spmm: out[r] = sum val * xin[col], no atomics ------
// one wave per row, lane = feature (64, padded)
__global__ __launch_bounds__(256) void k_gather(
    const int* __restrict__ ptr, const int2* __restrict__ sdat,
    const float* __restrict__ xin,
    float* __restrict__ out, int n)
{
    int r = blockIdx.x * 4 + (threadIdx.x >> 6);
    int lane = threadIdx.x & 63;
    if (r >= n) return;
    int s = (r == 0) ? 0 : ptr[r - 1];
    int e = ptr[r];
    float acc = 0.f;
    int k = s;
#pragma unroll 1
    for (; k + 1 < e; k += 2) {
        int2 d0 = sdat[k], d1 = sdat[k + 1];
        float x0 = xin[((size_t)d0.x << 6) + lane];
        float x1 = xin[((size_t)d1.x << 6) + lane];
        acc = fmaf(__int_as_float(d0.y), x0, acc);
        acc = fmaf(__int_as_float(d1.y), x1, acc);
    }
    if (k < e) {
        int2 d0 = sdat[k];
        acc = fmaf(__int_as_float(d0.y), xin[((size_t)d0.x << 6) + lane], acc);
    }
    out[((size_t)r << 6) + lane] = acc;
}

// ---------------- fallback spmm: COO scatter-atomic -------------------------
__global__ __launch_bounds__(256) void k_spmm(
    const int* __restrict__ rows, const int* __restrict__ cols,
    const float* __restrict__ val, const float* __restrict__ xin,
    float* __restrict__ acc, int nnz)
{
    int wave = blockIdx.x * 4 + (threadIdx.x >> 6);
    int lane = threadIdx.x & 63;
    int e0 = wave * NZPW;
#pragma unroll 1
    for (int k = 0; k < NZPW; ++k) {
        int e = e0 + k;
        if (e >= nnz) break;
        int r = rows[e];
        int c = cols[e];
        float v = val[e];
        float xv = xin[((size_t)c << 6) + lane];
        unsafeAtomicAdd(&acc[((size_t)r << 6) + lane], v * xv);
    }
}

// ------- combine: recompute self-MLP, add spmm2 result, classifier dot ------
__global__ __launch_bounds__(256) void k_combine(
    const float* __restrict__ x,
    const float* __restrict__ W1, const float* __restrict__ b1,
    const float* __restrict__ W2, const float* __restrict__ b2,
    const float* __restrict__ Wc, const float* __restrict__ bcp,
    const float* __restrict__ x2b,
    float* __restrict__ out, float* __restrict__ x3, int n)
{
    int t = blockIdx.x * 256 + threadIdx.x;
    if (t >= n) return;
    const float* xr = x + (size_t)t * FI;

    float h[FO];
#pragma unroll
    for (int j = 0; j < FO; ++j) h[j] = b1[j];
#pragma unroll 1
    for (int ii = 0; ii < FI; ii += 4) {
        float4 xq = *(const float4*)(xr + ii);
#pragma unroll
        for (int j = 0; j < FO; ++j) h[j] = fmaf(xq.x, W1[(ii+0)*FO+j], h[j]);
#pragma unroll
        for (int j = 0; j < FO; ++j) h[j] = fmaf(xq.y, W1[(ii+1)*FO+j], h[j]);
#pragma unroll
        for (int j = 0; j < FO; ++j) h[j] = fmaf(xq.z, W1[(ii+2)*FO+j], h[j]);
#pragma unroll
        for (int j = 0; j < FO; ++j) h[j] = fmaf(xq.w, W1[(ii+3)*FO+j], h[j]);
    }
#pragma unroll
    for (int j = 0; j < FO; ++j) h[j] = fmaxf(h[j], 0.f);

    float o[FO];
#pragma unroll
    for (int j = 0; j < FO; ++j) o[j] = b2[j];
#pragma unroll 1
    for (int i = 0; i < FO; ++i) {
        float hi = h[i];
#pragma unroll
        for (int j = 0; j < FO; ++j) o[j] = fmaf(hi, W2[i*FO+j], o[j]);
    }

    const float4* q4 = (const float4*)(x2b + (size_t)t * FP);
    float4* dst = (float4*)(out + (size_t)t * FP);
    float dot = 0.f;
#pragma unroll
    for (int c = 0; c < 15; ++c) {
        float4 q = q4[c];
        float4 w;
        w.x = q.x + fmaxf(o[4*c+0], 0.f);
        w.y = q.y + fmaxf(o[4*c+1], 0.f);
        w.z = q.z + fmaxf(o[4*c+2], 0.f);
        w.w = q.w + fmaxf(o[4*c+3], 0.f);
        dot = fmaf(w.x, Wc[4*c+0], dot);
        dot = fmaf(w.y, Wc[4*c+1], dot);
        dot = fmaf(w.z, Wc[4*c+2], dot);
        dot = fmaf(w.w, Wc[4*c+3], dot);
        dst[c] = w;
    }
    {
        float4 q = q4[15];
        float4 w;
        w.x = q.x + fmaxf(o[60], 0.f);
        w.y = q.y + fmaxf(o[61], 0.f);
        w.z = q.z + fmaxf(o[62], 0.f);
        w.w = 0.f;  // slot for sinkhorn channel (overwritten later)
        dot = fmaf(w.x, Wc[60], dot);
        dot = fmaf(w.y, Wc[61], dot);
        dot = fmaf(w.z, Wc[62], dot);
        dst[15] = w;
    }
    x3[t] = dot + bcp[0];
}

// ---------------- sinkhorn v5 ----------------------------------------------
// Scalar-offset form: log_s = u - R[a] - C[b]; u read-only (lives in AGPRs
// via compiler copies -> every access costs VALU issue, so minimize accesses).
// Iters 0,1: max-tracked two-pass (raw u unbounded).
// Iters 2..19: shift by the line's PREVIOUS offset. Provable bounds: terms
// u-R-C_old <= +16, per-line max >= -16 (offsets move <= 8/iter in log2),
// so fp32 never over/underflows the sum. One u-pass, sum-only merge:
// halves AGPR reads and exp2 count for 18 of 20 iterations.
__global__ __launch_bounds__(1024) __attribute__((amdgpu_waves_per_eu(4, 4)))
void k_sinkhorn(const float* __restrict__ x3, float* __restrict__ out)
{
    __shared__ float pm[256][41];   // [line][chunk] partial max (iters 0,1)
    __shared__ float ps[256][41];   // [line][chunk] partial sum
    __shared__ float Rl[256];       // row offsets (index a)
    __shared__ float Cl[256];       // col offsets (index b)
    const int tid = threadIdx.x;
    const int ta = tid >> 5, tb = tid & 31;     // tile coords
    const int line4 = tid >> 2, sub = tid & 3;  // merge coords: 4 threads/line

    float u[8][8];
#pragma unroll
    for (int i = 0; i < 8; ++i) {
        const float4* src = (const float4*)(x3 + (ta*8 + i)*256 + tb*8);
        float4 a0 = src[0], a1 = src[1];
        const float sc = INV_TAU * LOG2E;
        u[i][0] = a0.x * sc; u[i][1] = a0.y * sc;
        u[i][2] = a0.z * sc; u[i][3] = a0.w * sc;
        u[i][4] = a1.x * sc; u[i][5] = a1.y * sc;
        u[i][6] = a1.z * sc; u[i][7] = a1.w * sc;
    }
    if (tid < 256) { Rl[tid] = 0.f; Cl[tid] = 0.f; }
    __syncthreads();

    // ---- iters 0,1: max-tracked (v4 body) ----
#pragma unroll 1
    for (int it = 0; it < 2; ++it) {
        const bool even = (it & 1) == 0;
        if (even) {
            float r[8];
#pragma unroll
            for (int i = 0; i < 8; ++i) r[i] = Rl[ta*8 + i];
#pragma unroll
            for (int j = 0; j < 8; ++j) {
                float m = u[0][j] - r[0];
#pragma unroll
                for (int i = 1; i < 8; ++i) m = fmaxf(m, u[i][j] - r[i]);
                float s = 0.f;
#pragma unroll
                for (int i = 0; i < 8; ++i) s += exp2f(u[i][j] - r[i] - m);
                pm[tb*8 + j][ta] = m;
                ps[tb*8 + j][ta] = s;
            }
        } else {
            float c[8];
#pragma unroll
            for (int j = 0; j < 8; ++j) c[j] = Cl[tb*8 + j];
#pragma unroll
            for (int i = 0; i < 8; ++i) {
                float m = u[i][0] - c[0];
#pragma unroll
                for (int j = 1; j < 8; ++j) m = fmaxf(m, u[i][j] - c[j]);
                float s = 0.f;
#pragma unroll
                for (int j = 0; j < 8; ++j) s += exp2f(u[i][j] - c[j] - m);
                pm[ta*8 + i][tb] = m;
                ps[ta*8 + i][tb] = s;
            }
        }
        __syncthreads();
        float M = pm[line4][sub*8];
        float S = ps[line4][sub*8];
#pragma unroll
        for (int k = 1; k < 8; ++k) {
            float m2 = pm[line4][sub*8 + k];
            float s2 = ps[line4][sub*8 + k];
            float nm = fmaxf(M, m2);
            S = S * exp2f(M - nm) + s2 * exp2f(m2 - nm);
            M = nm;
        }
#pragma unroll
        for (int d = 1; d <= 2; d <<= 1) {
            float m2 = __shfl_xor(M, d);
            float s2 = __shfl_xor(S, d);
            float nm = fmaxf(M, m2);
            S = S * exp2f(M - nm) + s2 * exp2f(m2 - nm);
            M = nm;
        }
        if (sub == 0) {
            float l = M + log2f(S);
            if (even) Cl[line4] = l; else Rl[line4] = l;
        }
        __syncthreads();
    }

    // ---- iters 2..19: previous-offset shift, single pass, sum-only merge ---
#pragma unroll 1
    for (int it = 2; it < 20; ++it) {
        const bool even = (it & 1) == 0;
        float r[8], c[8];
#pragma unroll
        for (int i = 0; i < 8; ++i) r[i] = Rl[ta*8 + i];
#pragma unroll
        for (int j = 0; j < 8; ++j) c[j] = Cl[tb*8 + j];
        if (even) {
            // new C[b] = C_old[b] + log2( sum_a 2^(u - R[a] - C_old[b]) )
#pragma unroll
            for (int j = 0; j < 8; ++j) {
                float s = 0.f;
#pragma unroll
                for (int i = 0; i < 8; ++i) s += exp2f(u[i][j] - r[i] - c[j]);
                ps[tb*8 + j][ta] = s;
            }
        } else {
            // new R[a] = R_old[a] + log2( sum_b 2^(u - C[b] - R_old[a]) )
#pragma unroll
            for (int i = 0; i < 8; ++i) {
                float s = 0.f;
#pragma unroll
                for (int j = 0; j < 8; ++j) s += exp2f(u[i][j] - c[j] - r[i]);
                ps[ta*8 + i][tb] = s;
            }
        }
        __syncthreads();
        float S = 0.f;
#pragma unroll
        for (int k = 0; k < 8; ++k) S += ps[line4][sub*8 + k];
        S += __shfl_xor(S, 1);
        S += __shfl_xor(S, 2);
        if (sub == 0) {
            float d = log2f(S);
            if (even) Cl[line4] += d; else Rl[line4] += d;
        }
        __syncthreads();
    }

    float r[8], c[8];
#pragma unroll
    for (int i = 0; i < 8; ++i) r[i] = Rl[ta*8 + i];
#pragma unroll
    for (int j = 0; j < 8; ++j) c[j] = Cl[tb*8 + j];
#pragma unroll
    for (int i = 0; i < 8; ++i) {
        int a = ta*8 + i;
#pragma unroll
        for (int j = 0; j < 8; ++j) {
            out[((size_t)(a*256 + tb*8 + j) << 6) + 63] =
                exp2f(u[i][j] - r[i] - c[j]);
        }
    }
}

extern "C" void kernel_launch(void* const* d_in, const int* in_sizes, int n_in,
                              void* d_out, int out_size, void* d_ws, size_t ws_size,
                              hipStream_t stream)
{
    const float* K_value = (const float*)d_in[0];
    const int*   K_index = (const int*)d_in[1];
    const float* A_value = (const float*)d_in[2];
    const int*   A_index = (const int*)d_in[3];
    const float* x   = (const float*)d_in[4];
    const float* Wn1 = (const float*)d_in[5];
    const float* bn1 = (const float*)d_in[6];
    const float* Wn2 = (const float*)d_in[7];
    const float* bn2 = (const float*)d_in[8];
    const float* Ws1 = (const float*)d_in[9];
    const float* bs1 = (const float*)d_in[10];
    const float* Ws2 = (const float*)d_in[11];
    const float* bs2 = (const float*)d_in[12];
    const float* Wc  = (const float*)d_in[13];
    const float* bc  = (const float*)d_in[14];

    int nnzK = in_sizes[0];
    int nnzA = in_sizes[2];
    int n    = in_sizes[4] / FI;   // 65536

    float* outf = (float*)d_out;
    char*  ws   = (char*)d_ws;
    float* bufA = (float*)ws;                        // 16MB: x1 (padded), later x2
    float* x3   = bufA + (size_t)n * FP;             // 256KB
    int*   ptr  = (int*)(x3 + n);                    // 256KB row pointers/cursors
    int2*  sdat = (int2*)(ptr + n);                  // 8MB packed (col,val)
    size_t need = ((size_t)n * FP + n + n) * 4 + (size_t)nnzK * 8;

    // 1. n_func MLP -> bufA (x1, padded to 64)
    k_mlp_n<<<(n + 255) / 256, 256, 0, stream>>>(x, Wn1, bn1, Wn2, bn2, bufA, n);

    if (ws_size >= need && n == 65536) {
        // ---- CSR-gather path (no fp32 atomics) ----
        // K: build CSR, Wx(d_out) = K @ x1
        (void)hipMemsetAsync(ptr, 0, (size_t)n * 4, stream);
        k_hist<<<2048, 256, 0, stream>>>(K_index, ptr, nnzK);
        k_scan<<<1, 1024, 0, stream>>>(ptr);
        k_scatter<<<2048, 256, 0, stream>>>(K_index, K_index + nnzK, K_value,
                                            ptr, sdat, nnzK);
        k_gather<<<(n + 3) / 4, 256, 0, stream>>>(ptr, sdat, bufA, outf, n);
        // A: build CSR, x2(bufA) = A @ Wx
        (void)hipMemsetAsync(ptr, 0, (size_t)n * 4, stream);
        k_hist<<<2048, 256, 0, stream>>>(A_index, ptr, nnzA);
        k_scan<<<1, 1024, 0, stream>>>(ptr);
        k_scatter<<<2048, 256, 0, stream>>>(A_index, A_index + nnzA, A_value,
                                            ptr, sdat, nnzA);
        k_gather<<<(n + 3) / 4, 256, 0, stream>>>(ptr, sdat, outf, bufA, n);
    } else {
        // ---- fallback: atomic scatter path ----
        (void)hipMemsetAsync(outf, 0, (size_t)n * FP * 4, stream);
        int blocks1 = (nnzK + 4 * NZPW - 1) / (4 * NZPW);
        k_spmm<<<blocks1, 256, 0, stream>>>(K_index, K_index + nnzK, K_value,
                                            bufA, outf, nnzK);
        (void)hipMemsetAsync(bufA, 0, (size_t)n * FP * 4, stream);
        int blocks2 = (nnzA + 4 * NZPW - 1) / (4 * NZPW);
        k_spmm<<<blocks2, 256, 0, stream>>>(A_index, A_index + nnzA, A_value,
                                            outf, bufA, nnzA);
        // x2 lands in bufA either way
    }

    // combine: self-MLP + x2(bufA), write out[:, :63], classifier -> x3
    k_combine<<<(n + 255) / 256, 256, 0, stream>>>(x, Ws1, bs1, Ws2, bs2, Wc, bc,
                                                   bufA, outf, x3, n);
    // sinkhorn -> out[:, 63]
    k_sinkhorn<<<1, 1024, 0, stream>>>(x3, outf);
}

// Round 7
// 565.827 us; speedup vs baseline: 1.3184x; 1.0535x over previous
//
#include <hip/hip_runtime.h>
#include <hip/hip_bf16.h>

#define FI 64
#define FO 63
#define FP 64
#define NZPW 8
#define INV_TAU 20.0f
#define LOG2E 1.4426950408889634f

// raw gfx950 transcendentals: v_exp_f32 = 2^x, v_log_f32 = log2(x).
// OCML exp2f/log2f add denormal-fixup VALU ops we provably don't need
// (args bounded; denormal results are 0 in fp32 sums anyway).
__device__ __forceinline__ float fexp2(float x) {
    float y; asm("v_exp_f32 %0, %1" : "=v"(y) : "v"(x)); return y;
}
__device__ __forceinline__ float flog2(float x) {
    float y; asm("v_log_f32 %0, %1" : "=v"(y) : "v"(x)); return y;
}

// ---------------- MLP (n_func): x (n,64) -> x1 padded (n,64) ----------------
__global__ __launch_bounds__(256) void k_mlp_n(
    const float* __restrict__ x,
    const float* __restrict__ W1, const float* __restrict__ b1,
    const float* __restrict__ W2, const float* __restrict__ b2,
    float* __restrict__ x1p, int n)
{
    int t = blockIdx.x * 256 + threadIdx.x;
    if (t >= n) return;
    const float* xr = x + (size_t)t * FI;

    float h[FO];
#pragma unroll
    for (int j = 0; j < FO; ++j) h[j] = b1[j];
#pragma unroll 1
    for (int ii = 0; ii < FI; ii += 4) {
        float4 xq = *(const float4*)(xr + ii);
#pragma unroll
        for (int j = 0; j < FO; ++j) h[j] = fmaf(xq.x, W1[(ii+0)*FO+j], h[j]);
#pragma unroll
        for (int j = 0; j < FO; ++j) h[j] = fmaf(xq.y, W1[(ii+1)*FO+j], h[j]);
#pragma unroll
        for (int j = 0; j < FO; ++j) h[j] = fmaf(xq.z, W1[(ii+2)*FO+j], h[j]);
#pragma unroll
        for (int j = 0; j < FO; ++j) h[j] = fmaf(xq.w, W1[(ii+3)*FO+j], h[j]);
    }
#pragma unroll
    for (int j = 0; j < FO; ++j) h[j] = fmaxf(h[j], 0.f);

    float o[FO];
#pragma unroll
    for (int j = 0; j < FO; ++j) o[j] = b2[j];
#pragma unroll 1
    for (int i = 0; i < FO; ++i) {
        float hi = h[i];
#pragma unroll
        for (int j = 0; j < FO; ++j) o[j] = fmaf(hi, W2[i*FO+j], o[j]);
    }

    float* dst = x1p + (size_t)t * FP;
#pragma unroll
    for (int c = 0; c < 15; ++c) {
        float4 w;
        w.x = fmaxf(o[4*c+0], 0.f);
        w.y = fmaxf(o[4*c+1], 0.f);
        w.z = fmaxf(o[4*c+2], 0.f);
        w.w = fmaxf(o[4*c+3], 0.f);
        ((float4*)dst)[c] = w;
    }
    {
        float4 w;
        w.x = fmaxf(o[60], 0.f);
        w.y = fmaxf(o[61], 0.f);
        w.z = fmaxf(o[62], 0.f);
        w.w = 0.f;  // pad column stays zero
        ((float4*)dst)[15] = w;
    }
}

// ---------------- CSR build: histogram / scan / scatter ---------------------
__global__ __launch_bounds__(256) void k_hist(
    const int* __restrict__ rows, int* __restrict__ cnt, int nnz)
{
    int i = blockIdx.x * 256 + threadIdx.x;
    int stride = gridDim.x * 256;
    for (; i < nnz; i += stride) atomicAdd(&cnt[rows[i]], 1);
}

// in-place exclusive scan of 65536 ints: 1024 threads x 64 bins each
__global__ __launch_bounds__(1024) void k_scan(int* __restrict__ ptr)
{
    __shared__ int tot[1024];
    int t = threadIdx.x;
    int4* p4 = (int4*)(ptr + t * 64);
    int sum = 0;
#pragma unroll 1
    for (int q = 0; q < 16; ++q) {
        int4 b = p4[q];
        sum += b.x + b.y + b.z + b.w;
    }
    tot[t] = sum;
    __syncthreads();
#pragma unroll 1
    for (int off = 1; off < 1024; off <<= 1) {
        int v2 = 0;
        if (t >= off) v2 = tot[t - off];
        __syncthreads();
        if (t >= off) tot[t] += v2;
        __syncthreads();
    }
    int off = (t == 0) ? 0 : tot[t - 1];
#pragma unroll 1
    for (int q = 0; q < 16; ++q) {
        int4 b = p4[q];
        int4 w;
        w.x = off; off += b.x;
        w.y = off; off += b.y;
        w.z = off; off += b.z;
        w.w = off; off += b.w;
        p4[q] = w;
    }
}

// packed scatter: one 8B store per entry (col, val) instead of two 4B stores
__global__ __launch_bounds__(256) void k_scatter(
    const int* __restrict__ rows, const int* __restrict__ cols,
    const float* __restrict__ val, int* __restrict__ ptr,
    int2* __restrict__ sdat, int nnz)
{
    int i = blockIdx.x * 256 + threadIdx.x;
    int stride = gridDim.x * 256;
    for (; i < nnz; i += stride) {
        int p = atomicAdd(&ptr[rows[i]], 1);
        sdat[p] = make_int2(cols[i], __float_as_int(val[i]));
    }
}

// ---------------- gather spmm: out[r] = sum val * xin[col], no atomics ------
// one wave per row, lane = feature (64, padded)
__global__ __launch_bounds__(256) void k_gather(
    const int* __restrict__ ptr, const int2* __restrict__ sdat,
    const float* __restrict__ xin,
    float* __restrict__ out, int n)
{
    int r = blockIdx.x * 4 + (threadIdx.x >> 6);
    int lane = threadIdx.x & 63;
    if (r >= n) return;
    int s = (r == 0) ? 0 : ptr[r - 1];
    int e = ptr[r];
    float acc = 0.f;
    int k = s;
#pragma unroll 1
    for (; k + 1 < e; k += 2) {
        int2 d0 = sdat[k], d1 = sdat[k + 1];
        float x0 = xin[((size_t)d0.x << 6) + lane];
        float x1 = xin[((size_t)d1.x << 6) + lane];
        acc = fmaf(__int_as_float(d0.y), x0, acc);
        acc = fmaf(__int_as_float(d1.y), x1, acc);
    }
    if (k < e) {
        int2 d0 = sdat[k];
        acc = fmaf(__int_as_float(d0.y), xin[((size_t)d0.x << 6) + lane], acc);
    }
    out[((size_t)r << 6) + lane] = acc;
}

// ---------------- fallback spmm: COO scatter-atomic -------------------------
__global__ __launch_bounds__(256) void k_spmm(
    const int* __restrict__ rows, const int* __restrict__ cols,
    const float* __restrict__ val, const float* __restrict__ xin,
    float* __restrict__ acc, int nnz)
{
    int wave = blockIdx.x * 4 + (threadIdx.x >> 6);
    int lane = threadIdx.x & 63;
    int e0 = wave * NZPW;
#pragma unroll 1
    for (int k = 0; k < NZPW; ++k) {
        int e = e0 + k;
        if (e >= nnz) break;
        int r = rows[e];
        int c = cols[e];
        float v = val[e];
        float xv = xin[((size_t)c << 6) + lane];
        unsafeAtomicAdd(&acc[((size_t)r << 6) + lane], v * xv);
    }
}

// ------- combine: recompute self-MLP, add spmm2 result, classifier dot ------
__global__ __launch_bounds__(256) void k_combine(
    const float* __restrict__ x,
    const float* __restrict__ W1, const float* __restrict__ b1,
    const float* __restrict__ W2, const float* __restrict__ b2,
    const float* __restrict__ Wc, const float* __restrict__ bcp,
    const float* __restrict__ x2b,
    float* __restrict__ out, float* __restrict__ x3, int n)
{
    int t = blockIdx.x * 256 + threadIdx.x;
    if (t >= n) return;
    const float* xr = x + (size_t)t * FI;

    float h[FO];
#pragma unroll
    for (int j = 0; j < FO; ++j) h[j] = b1[j];
#pragma unroll 1
    for (int ii = 0; ii < FI; ii += 4) {
        float4 xq = *(const float4*)(xr + ii);
#pragma unroll
        for (int j = 0; j < FO; ++j) h[j] = fmaf(xq.x, W1[(ii+0)*FO+j], h[j]);
#pragma unroll
        for (int j = 0; j < FO; ++j) h[j] = fmaf(xq.y, W1[(ii+1)*FO+j], h[j]);
#pragma unroll
        for (int j = 0; j < FO; ++j) h[j] = fmaf(xq.z, W1[(ii+2)*FO+j], h[j]);
#pragma unroll
        for (int j = 0; j < FO; ++j) h[j] = fmaf(xq.w, W1[(ii+3)*FO+j], h[j]);
    }
#pragma unroll
    for (int j = 0; j < FO; ++j) h[j] = fmaxf(h[j], 0.f);

    float o[FO];
#pragma unroll
    for (int j = 0; j < FO; ++j) o[j] = b2[j];
#pragma unroll 1
    for (int i = 0; i < FO; ++i) {
        float hi = h[i];
#pragma unroll
        for (int j = 0; j < FO; ++j) o[j] = fmaf(hi, W2[i*FO+j], o[j]);
    }

    const float4* q4 = (const float4*)(x2b + (size_t)t * FP);
    float4* dst = (float4*)(out + (size_t)t * FP);
    float dot = 0.f;
#pragma unroll
    for (int c = 0; c < 15; ++c) {
        float4 q = q4[c];
        float4 w;
        w.x = q.x + fmaxf(o[4*c+0], 0.f);
        w.y = q.y + fmaxf(o[4*c+1], 0.f);
        w.z = q.z + fmaxf(o[4*c+2], 0.f);
        w.w = q.w + fmaxf(o[4*c+3], 0.f);
        dot = fmaf(w.x, Wc[4*c+0], dot);
        dot = fmaf(w.y, Wc[4*c+1], dot);
        dot = fmaf(w.z, Wc[4*c+2], dot);
        dot = fmaf(w.w, Wc[4*c+3], dot);
        dst[c] = w;
    }
    {
        float4 q = q4[15];
        float4 w;
        w.x = q.x + fmaxf(o[60], 0.f);
        w.y = q.y + fmaxf(o[61], 0.f);
        w.z = q.z + fmaxf(o[62], 0.f);
        w.w = 0.f;  // slot for sinkhorn channel (overwritten later)
        dot = fmaf(w.x, Wc[60], dot);
        dot = fmaf(w.y, Wc[61], dot);
        dot = fmaf(w.z, Wc[62], dot);
        dst[15] = w;
    }
    x3[t] = dot + bcp[0];
}

// ---------------- sinkhorn v6 ----------------------------------------------
// Scalar-offset form (log_s = u - R[a] - C[b], u read-only in regs).
// v6: (a) raw v_exp_f32/v_log_f32 via inline asm (kills OCML denormal-fixup
// VALU expansion — the round-6 bottleneck); (b) partials in [chunk][line]
// layout, each thread writes its 8 partials as 2x ds_write_b128 (32B lane
// stride ~ 2-way, free) instead of 8-way-conflicted scalar stores.
// Iters 0,1 max-tracked; iters 2..19 previous-offset shift (args <= +16).
#define SKP 332   // row stride (floats): 332*4B = 83*16B -> float4-aligned rows
__global__ __launch_bounds__(1024) __attribute__((amdgpu_waves_per_eu(4, 4)))
void k_sinkhorn(const float* __restrict__ x3, float* __restrict__ out)
{
    __shared__ float pm[32][SKP];   // [chunk][line] partial max (iters 0,1)
    __shared__ float ps[32][SKP];   // [chunk][line] partial sum
    __shared__ float Rl[256];       // row offsets (index a)
    __shared__ float Cl[256];       // col offsets (index b)
    const int tid = threadIdx.x;
    const int ta = tid >> 5, tb = tid & 31;     // tile coords
    const int line4 = tid >> 2, sub = tid & 3;  // merge coords: 4 threads/line

    float u[8][8];
#pragma unroll
    for (int i = 0; i < 8; ++i) {
        const float4* src = (const float4*)(x3 + (ta*8 + i)*256 + tb*8);
        float4 a0 = src[0], a1 = src[1];
        const float sc = INV_TAU * LOG2E;
        u[i][0] = a0.x * sc; u[i][1] = a0.y * sc;
        u[i][2] = a0.z * sc; u[i][3] = a0.w * sc;
        u[i][4] = a1.x * sc; u[i][5] = a1.y * sc;
        u[i][6] = a1.z * sc; u[i][7] = a1.w * sc;
    }
    if (tid < 256) { Rl[tid] = 0.f; Cl[tid] = 0.f; }
    __syncthreads();

    // ---- iters 0,1: max-tracked (raw u unbounded) ----
#pragma unroll 1
    for (int it = 0; it < 2; ++it) {
        const bool even = (it & 1) == 0;
        float sm[8], ss[8];
        if (even) {
            float r[8];
#pragma unroll
            for (int i = 0; i < 8; ++i) r[i] = Rl[ta*8 + i];
#pragma unroll
            for (int j = 0; j < 8; ++j) {
                float m = u[0][j] - r[0];
#pragma unroll
                for (int i = 1; i < 8; ++i) m = fmaxf(m, u[i][j] - r[i]);
                float s0 = 0.f, s1 = 0.f;
#pragma unroll
                for (int i = 0; i < 8; i += 2) {
                    s0 += fexp2(u[i][j] - r[i] - m);
                    s1 += fexp2(u[i+1][j] - r[i+1] - m);
                }
                sm[j] = m; ss[j] = s0 + s1;
            }
        } else {
            float c[8];
#pragma unroll
            for (int j = 0; j < 8; ++j) c[j] = Cl[tb*8 + j];
#pragma unroll
            for (int i = 0; i < 8; ++i) {
                float m = u[i][0] - c[0];
#pragma unroll
                for (int j = 1; j < 8; ++j) m = fmaxf(m, u[i][j] - c[j]);
                float s0 = 0.f, s1 = 0.f;
#pragma unroll
                for (int j = 0; j < 8; j += 2) {
                    s0 += fexp2(u[i][j] - c[j] - m);
                    s1 += fexp2(u[i][j+1] - c[j+1] - m);
                }
                sm[i] = m; ss[i] = s0 + s1;
            }
        }
        // chunk = (even ? ta : tb), line base = (even ? tb : ta)*8
        {
            float* mrow = even ? &pm[ta][tb*8] : &pm[tb][ta*8];
            float* srow = even ? &ps[ta][tb*8] : &ps[tb][ta*8];
            ((float4*)mrow)[0] = make_float4(sm[0], sm[1], sm[2], sm[3]);
            ((float4*)mrow)[1] = make_float4(sm[4], sm[5], sm[6], sm[7]);
            ((float4*)srow)[0] = make_float4(ss[0], ss[1], ss[2], ss[3]);
            ((float4*)srow)[1] = make_float4(ss[4], ss[5], ss[6], ss[7]);
        }
        __syncthreads();
        float M = pm[sub*8][line4];
        float S = ps[sub*8][line4];
#pragma unroll
        for (int k = 1; k < 8; ++k) {
            float m2 = pm[sub*8 + k][line4];
            float s2 = ps[sub*8 + k][line4];
            float nm = fmaxf(M, m2);
            S = S * fexp2(M - nm) + s2 * fexp2(m2 - nm);
            M = nm;
        }
#pragma unroll
        for (int d = 1; d <= 2; d <<= 1) {
            float m2 = __shfl_xor(M, d);
            float s2 = __shfl_xor(S, d);
            float nm = fmaxf(M, m2);
            S = S * fexp2(M - nm) + s2 * fexp2(m2 - nm);
            M = nm;
        }
        if (sub == 0) {
            float l = M + flog2(S);
            if (even) Cl[line4] = l; else Rl[line4] = l;
        }
        __syncthreads();
    }

    // ---- iters 2..19: previous-offset shift, single pass, sum-only merge ---
#pragma unroll 1
    for (int it = 2; it < 20; ++it) {
        const bool even = (it & 1) == 0;
        float r[8], c[8], ss[8];
#pragma unroll
        for (int i = 0; i < 8; ++i) r[i] = Rl[ta*8 + i];
#pragma unroll
        for (int j = 0; j < 8; ++j) c[j] = Cl[tb*8 + j];
        if (even) {
            // new C[b] = C_old[b] + log2( sum_a 2^(u - R[a] - C_old[b]) )
#pragma unroll
            for (int j = 0; j < 8; ++j) {
                float s0 = 0.f, s1 = 0.f;
#pragma unroll
                for (int i = 0; i < 8; i += 2) {
                    s0 += fexp2(u[i][j] - r[i] - c[j]);
                    s1 += fexp2(u[i+1][j] - r[i+1] - c[j]);
                }
                ss[j] = s0 + s1;
            }
        } else {
            // new R[a] = R_old[a] + log2( sum_b 2^(u - C[b] - R_old[a]) )
#pragma unroll
            for (int i = 0; i < 8; ++i) {
                float s0 = 0.f, s1 = 0.f;
#pragma unroll
                for (int j = 0; j < 8; j += 2) {
                    s0 += fexp2(u[i][j] - c[j] - r[i]);
                    s1 += fexp2(u[i][j+1] - c[j+1] - r[i]);
                }
                ss[i] = s0 + s1;
            }
        }
        {
            float* srow = even ? &ps[ta][tb*8] : &ps[tb][ta*8];
            ((float4*)srow)[0] = make_float4(ss[0], ss[1], ss[2], ss[3]);
            ((float4*)srow)[1] = make_float4(ss[4], ss[5], ss[6], ss[7]);
        }
        __syncthreads();
        float S = 0.f;
#pragma unroll
        for (int k = 0; k < 8; ++k) S += ps[sub*8 + k][line4];
        S += __shfl_xor(S, 1);
        S += __shfl_xor(S, 2);
        if (sub == 0) {
            float d = flog2(S);
            if (even) Cl[line4] += d; else Rl[line4] += d;
        }
        __syncthreads();
    }

    float r[8], c[8];
#pragma unroll
    for (int i = 0; i < 8; ++i) r[i] = Rl[ta*8 + i];
#pragma unroll
    for (int j = 0; j < 8; ++j) c[j] = Cl[tb*8 + j];
#pragma unroll
    for (int i = 0; i < 8; ++i) {
        int a = ta*8 + i;
#pragma unroll
        for (int j = 0; j < 8; ++j) {
            out[((size_t)(a*256 + tb*8 + j) << 6) + 63] =
                fexp2(u[i][j] - r[i] - c[j]);
        }
    }
}

extern "C" void kernel_launch(void* const* d_in, const int* in_sizes, int n_in,
                              void* d_out, int out_size, void* d_ws, size_t ws_size,
                              hipStream_t stream)
{
    const float* K_value = (const float*)d_in[0];
    const int*   K_index = (const int*)d_in[1];
    const float* A_value = (const float*)d_in[2];
    const int*   A_index = (const int*)d_in[3];
    const float* x   = (const float*)d_in[4];
    const float* Wn1 = (const float*)d_in[5];
    const float* bn1 = (const float*)d_in[6];
    const float* Wn2 = (const float*)d_in[7];
    const float* bn2 = (const float*)d_in[8];
    const float* Ws1 = (const float*)d_in[9];
    const float* bs1 = (const float*)d_in[10];
    const float* Ws2 = (const float*)d_in[11];
    const float* bs2 = (const float*)d_in[12];
    const float* Wc  = (const float*)d_in[13];
    const float* bc  = (const float*)d_in[14];

    int nnzK = in_sizes[0];
    int nnzA = in_sizes[2];
    int n    = in_sizes[4] / FI;   // 65536

    float* outf = (float*)d_out;
    char*  ws   = (char*)d_ws;
    float* bufA = (float*)ws;                        // 16MB: x1 (padded), later x2
    float* x3   = bufA + (size_t)n * FP;             // 256KB
    int*   ptr  = (int*)(x3 + n);                    // 256KB row pointers/cursors
    int2*  sdat = (int2*)(ptr + n);                  // 8MB packed (col,val)
    size_t need = ((size_t)n * FP + n + n) * 4 + (size_t)nnzK * 8;

    // 1. n_func MLP -> bufA (x1, padded to 64)
    k_mlp_n<<<(n + 255) / 256, 256, 0, stream>>>(x, Wn1, bn1, Wn2, bn2, bufA, n);

    if (ws_size >= need && n == 65536) {
        // ---- CSR-gather path (no fp32 atomics) ----
        // K: build CSR, Wx(d_out) = K @ x1
        (void)hipMemsetAsync(ptr, 0, (size_t)n * 4, stream);
        k_hist<<<2048, 256, 0, stream>>>(K_index, ptr, nnzK);
        k_scan<<<1, 1024, 0, stream>>>(ptr);
        k_scatter<<<2048, 256, 0, stream>>>(K_index, K_index + nnzK, K_value,
                                            ptr, sdat, nnzK);
        k_gather<<<(n + 3) / 4, 256, 0, stream>>>(ptr, sdat, bufA, outf, n);
        // A: build CSR, x2(bufA) = A @ Wx
        (void)hipMemsetAsync(ptr, 0, (size_t)n * 4, stream);
        k_hist<<<2048, 256, 0, stream>>>(A_index, ptr, nnzA);
        k_scan<<<1, 1024, 0, stream>>>(ptr);
        k_scatter<<<2048, 256, 0, stream>>>(A_index, A_index + nnzA, A_value,
                                            ptr, sdat, nnzA);
        k_gather<<<(n + 3) / 4, 256, 0, stream>>>(ptr, sdat, outf, bufA, n);
    } else {
        // ---- fallback: atomic scatter path ----
        (void)hipMemsetAsync(outf, 0, (size_t)n * FP * 4, stream);
        int blocks1 = (nnzK + 4 * NZPW - 1) / (4 * NZPW);
        k_spmm<<<blocks1, 256, 0, stream>>>(K_index, K_index + nnzK, K_value,
                                            bufA, outf, nnzK);
        (void)hipMemsetAsync(bufA, 0, (size_t)n * FP * 4, stream);
        int blocks2 = (nnzA + 4 * NZPW - 1) / (4 * NZPW);
        k_spmm<<<blocks2, 256, 0, stream>>>(A_index, A_index + nnzA, A_value,
                                            outf, bufA, nnzA);
        // x2 lands in bufA either way
    }

    // combine: self-MLP + x2(bufA), write out[:, :63], classifier -> x3
    k_combine<<<(n + 255) / 256, 256, 0, stream>>>(x, Ws1, bs1, Ws2, bs2, Wc, bc,
                                                   bufA, outf, x3, n);
    // sinkhorn -> out[:, 63]
    k_sinkhorn<<<1, 1024, 0, stream>>>(x3, outf);
}

// Round 8
// 518.297 us; speedup vs baseline: 1.4393x; 1.0917x over previous
//
#include <hip/hip_runtime.h>
#include <hip/hip_bf16.h>

#define FI 64
#define FO 63
#define FP 64
#define NZPW 8
#define INV_TAU 20.0f
#define LOG2E 1.4426950408889634f

// raw gfx950 transcendentals: v_exp_f32 = 2^x, v_log_f32 = log2(x).
__device__ __forceinline__ float fexp2(float x) {
    float y; asm("v_exp_f32 %0, %1" : "=v"(y) : "v"(x)); return y;
}
__device__ __forceinline__ float flog2(float x) {
    float y; asm("v_log_f32 %0, %1" : "=v"(y) : "v"(x)); return y;
}

// ---------------- MLP (n_func): x (n,64) -> x1 padded (n,64) ----------------
__global__ __launch_bounds__(256) void k_mlp_n(
    const float* __restrict__ x,
    const float* __restrict__ W1, const float* __restrict__ b1,
    const float* __restrict__ W2, const float* __restrict__ b2,
    float* __restrict__ x1p, int n)
{
    int t = blockIdx.x * 256 + threadIdx.x;
    if (t >= n) return;
    const float* xr = x + (size_t)t * FI;

    float h[FO];
#pragma unroll
    for (int j = 0; j < FO; ++j) h[j] = b1[j];
#pragma unroll 1
    for (int ii = 0; ii < FI; ii += 4) {
        float4 xq = *(const float4*)(xr + ii);
#pragma unroll
        for (int j = 0; j < FO; ++j) h[j] = fmaf(xq.x, W1[(ii+0)*FO+j], h[j]);
#pragma unroll
        for (int j = 0; j < FO; ++j) h[j] = fmaf(xq.y, W1[(ii+1)*FO+j], h[j]);
#pragma unroll
        for (int j = 0; j < FO; ++j) h[j] = fmaf(xq.z, W1[(ii+2)*FO+j], h[j]);
#pragma unroll
        for (int j = 0; j < FO; ++j) h[j] = fmaf(xq.w, W1[(ii+3)*FO+j], h[j]);
    }
#pragma unroll
    for (int j = 0; j < FO; ++j) h[j] = fmaxf(h[j], 0.f);

    float o[FO];
#pragma unroll
    for (int j = 0; j < FO; ++j) o[j] = b2[j];
#pragma unroll 1
    for (int i = 0; i < FO; ++i) {
        float hi = h[i];
#pragma unroll
        for (int j = 0; j < FO; ++j) o[j] = fmaf(hi, W2[i*FO+j], o[j]);
    }

    float* dst = x1p + (size_t)t * FP;
#pragma unroll
    for (int c = 0; c < 15; ++c) {
        float4 w;
        w.x = fmaxf(o[4*c+0], 0.f);
        w.y = fmaxf(o[4*c+1], 0.f);
        w.z = fmaxf(o[4*c+2], 0.f);
        w.w = fmaxf(o[4*c+3], 0.f);
        ((float4*)dst)[c] = w;
    }
    {
        float4 w;
        w.x = fmaxf(o[60], 0.f);
        w.y = fmaxf(o[61], 0.f);
        w.z = fmaxf(o[62], 0.f);
        w.w = 0.f;  // pad column stays zero
        ((float4*)dst)[15] = w;
    }
}

// -------- fused CSR build: one histogram pass over BOTH matrices ------------
__global__ __launch_bounds__(256) void k_hist2(
    const int* __restrict__ rowsK, const int* __restrict__ rowsA,
    int* __restrict__ cntK, int* __restrict__ cntA, int nnzK, int nnzA)
{
    int i = blockIdx.x * 256 + threadIdx.x;
    int stride = gridDim.x * 256;
    int total = nnzK + nnzA;
    for (; i < total; i += stride) {
        if (i < nnzK) atomicAdd(&cntK[rowsK[i]], 1);
        else          atomicAdd(&cntA[rowsA[i - nnzK]], 1);
    }
}

// in-place exclusive scan of 65536 ints; grid=2 scans two tables
__global__ __launch_bounds__(1024) void k_scan2(
    int* __restrict__ ptrK, int* __restrict__ ptrA)
{
    __shared__ int tot[1024];
    int* ptr = (blockIdx.x == 0) ? ptrK : ptrA;
    int t = threadIdx.x;
    int4* p4 = (int4*)(ptr + t * 64);
    int sum = 0;
#pragma unroll 1
    for (int q = 0; q < 16; ++q) {
        int4 b = p4[q];
        sum += b.x + b.y + b.z + b.w;
    }
    tot[t] = sum;
    __syncthreads();
#pragma unroll 1
    for (int off = 1; off < 1024; off <<= 1) {
        int v2 = 0;
        if (t >= off) v2 = tot[t - off];
        __syncthreads();
        if (t >= off) tot[t] += v2;
        __syncthreads();
    }
    int off = (t == 0) ? 0 : tot[t - 1];
#pragma unroll 1
    for (int q = 0; q < 16; ++q) {
        int4 b = p4[q];
        int4 w;
        w.x = off; off += b.x;
        w.y = off; off += b.y;
        w.z = off; off += b.z;
        w.w = off; off += b.w;
        p4[q] = w;
    }
}

// fused scatter for both matrices; packed (col,val) 8B stores
__global__ __launch_bounds__(256) void k_scatter2(
    const int* __restrict__ rowsK, const int* __restrict__ colsK,
    const float* __restrict__ valK,
    const int* __restrict__ rowsA, const int* __restrict__ colsA,
    const float* __restrict__ valA,
    int* __restrict__ ptrK, int* __restrict__ ptrA,
    int2* __restrict__ sdatK, int2* __restrict__ sdatA, int nnzK, int nnzA)
{
    int i = blockIdx.x * 256 + threadIdx.x;
    int stride = gridDim.x * 256;
    int total = nnzK + nnzA;
    for (; i < total; i += stride) {
        if (i < nnzK) {
            int p = atomicAdd(&ptrK[rowsK[i]], 1);
            sdatK[p] = make_int2(colsK[i], __float_as_int(valK[i]));
        } else {
            int j = i - nnzK;
            int p = atomicAdd(&ptrA[rowsA[j]], 1);
            sdatA[p] = make_int2(colsA[j], __float_as_int(valA[j]));
        }
    }
}

// ---------------- gather spmm, unroll-4: 4 loads in flight ------------------
__global__ __launch_bounds__(256) void k_gather(
    const int* __restrict__ ptr, const int2* __restrict__ sdat,
    const float* __restrict__ xin,
    float* __restrict__ out, int n)
{
    int r = blockIdx.x * 4 + (threadIdx.x >> 6);
    int lane = threadIdx.x & 63;
    if (r >= n) return;
    int s = (r == 0) ? 0 : ptr[r - 1];
    int e = ptr[r];
    float acc = 0.f;
    int k = s;
#pragma unroll 1
    for (; k + 3 < e; k += 4) {
        int2 d0 = sdat[k],     d1 = sdat[k + 1];
        int2 d2 = sdat[k + 2], d3 = sdat[k + 3];
        float x0 = xin[((size_t)d0.x << 6) + lane];
        float x1 = xin[((size_t)d1.x << 6) + lane];
        float x2 = xin[((size_t)d2.x << 6) + lane];
        float x3 = xin[((size_t)d3.x << 6) + lane];
        acc = fmaf(__int_as_float(d0.y), x0, acc);
        acc = fmaf(__int_as_float(d1.y), x1, acc);
        acc = fmaf(__int_as_float(d2.y), x2, acc);
        acc = fmaf(__int_as_float(d3.y), x3, acc);
    }
#pragma unroll 1
    for (; k < e; ++k) {
        int2 d0 = sdat[k];
        acc = fmaf(__int_as_float(d0.y), xin[((size_t)d0.x << 6) + lane], acc);
    }
    out[((size_t)r << 6) + lane] = acc;
}

// ---------------- tier-2 sequential CSR build helpers -----------------------
__global__ __launch_bounds__(256) void k_hist(
    const int* __restrict__ rows, int* __restrict__ cnt, int nnz)
{
    int i = blockIdx.x * 256 + threadIdx.x;
    int stride = gridDim.x * 256;
    for (; i < nnz; i += stride) atomicAdd(&cnt[rows[i]], 1);
}

__global__ __launch_bounds__(256) void k_scatter(
    const int* __restrict__ rows, const int* __restrict__ cols,
    const float* __restrict__ val, int* __restrict__ ptr,
    int2* __restrict__ sdat, int nnz)
{
    int i = blockIdx.x * 256 + threadIdx.x;
    int stride = gridDim.x * 256;
    for (; i < nnz; i += stride) {
        int p = atomicAdd(&ptr[rows[i]], 1);
        sdat[p] = make_int2(cols[i], __float_as_int(val[i]));
    }
}

// ---------------- tier-3 fallback spmm: COO scatter-atomic ------------------
__global__ __launch_bounds__(256) void k_spmm(
    const int* __restrict__ rows, const int* __restrict__ cols,
    const float* __restrict__ val, const float* __restrict__ xin,
    float* __restrict__ acc, int nnz)
{
    int wave = blockIdx.x * 4 + (threadIdx.x >> 6);
    int lane = threadIdx.x & 63;
    int e0 = wave * NZPW;
#pragma unroll 1
    for (int k = 0; k < NZPW; ++k) {
        int e = e0 + k;
        if (e >= nnz) break;
        int r = rows[e];
        int c = cols[e];
        float v = val[e];
        float xv = xin[((size_t)c << 6) + lane];
        unsafeAtomicAdd(&acc[((size_t)r << 6) + lane], v * xv);
    }
}

// ------- combine: recompute self-MLP, add spmm2 result, classifier dot ------
__global__ __launch_bounds__(256) void k_combine(
    const float* __restrict__ x,
    const float* __restrict__ W1, const float* __restrict__ b1,
    const float* __restrict__ W2, const float* __restrict__ b2,
    const float* __restrict__ Wc, const float* __restrict__ bcp,
    const float* __restrict__ x2b,
    float* __restrict__ out, float* __restrict__ x3, int n)
{
    int t = blockIdx.x * 256 + threadIdx.x;
    if (t >= n) return;
    const float* xr = x + (size_t)t * FI;

    float h[FO];
#pragma unroll
    for (int j = 0; j < FO; ++j) h[j] = b1[j];
#pragma unroll 1
    for (int ii = 0; ii < FI; ii += 4) {
        float4 xq = *(const float4*)(xr + ii);
#pragma unroll
        for (int j = 0; j < FO; ++j) h[j] = fmaf(xq.x, W1[(ii+0)*FO+j], h[j]);
#pragma unroll
        for (int j = 0; j < FO; ++j) h[j] = fmaf(xq.y, W1[(ii+1)*FO+j], h[j]);
#pragma unroll
        for (int j = 0; j < FO; ++j) h[j] = fmaf(xq.z, W1[(ii+2)*FO+j], h[j]);
#pragma unroll
        for (int j = 0; j < FO; ++j) h[j] = fmaf(xq.w, W1[(ii+3)*FO+j], h[j]);
    }
#pragma unroll
    for (int j = 0; j < FO; ++j) h[j] = fmaxf(h[j], 0.f);

    float o[FO];
#pragma unroll
    for (int j = 0; j < FO; ++j) o[j] = b2[j];
#pragma unroll 1
    for (int i = 0; i < FO; ++i) {
        float hi = h[i];
#pragma unroll
        for (int j = 0; j < FO; ++j) o[j] = fmaf(hi, W2[i*FO+j], o[j]);
    }

    const float4* q4 = (const float4*)(x2b + (size_t)t * FP);
    float4* dst = (float4*)(out + (size_t)t * FP);
    float dot = 0.f;
#pragma unroll
    for (int c = 0; c < 15; ++c) {
        float4 q = q4[c];
        float4 w;
        w.x = q.x + fmaxf(o[4*c+0], 0.f);
        w.y = q.y + fmaxf(o[4*c+1], 0.f);
        w.z = q.z + fmaxf(o[4*c+2], 0.f);
        w.w = q.w + fmaxf(o[4*c+3], 0.f);
        dot = fmaf(w.x, Wc[4*c+0], dot);
        dot = fmaf(w.y, Wc[4*c+1], dot);
        dot = fmaf(w.z, Wc[4*c+2], dot);
        dot = fmaf(w.w, Wc[4*c+3], dot);
        dst[c] = w;
    }
    {
        float4 q = q4[15];
        float4 w;
        w.x = q.x + fmaxf(o[60], 0.f);
        w.y = q.y + fmaxf(o[61], 0.f);
        w.z = q.z + fmaxf(o[62], 0.f);
        w.w = 0.f;  // slot for sinkhorn channel (overwritten later)
        dot = fmaf(w.x, Wc[60], dot);
        dot = fmaf(w.y, Wc[61], dot);
        dot = fmaf(w.z, Wc[62], dot);
        dst[15] = w;
    }
    x3[t] = dot + bcp[0];
}

// ---------------- sinkhorn v6 (unchanged from round 7) ----------------------
#define SKP 332
__global__ __launch_bounds__(1024) __attribute__((amdgpu_waves_per_eu(4, 4)))
void k_sinkhorn(const float* __restrict__ x3, float* __restrict__ out)
{
    __shared__ float pm[32][SKP];
    __shared__ float ps[32][SKP];
    __shared__ float Rl[256];
    __shared__ float Cl[256];
    const int tid = threadIdx.x;
    const int ta = tid >> 5, tb = tid & 31;
    const int line4 = tid >> 2, sub = tid & 3;

    float u[8][8];
#pragma unroll
    for (int i = 0; i < 8; ++i) {
        const float4* src = (const float4*)(x3 + (ta*8 + i)*256 + tb*8);
        float4 a0 = src[0], a1 = src[1];
        const float sc = INV_TAU * LOG2E;
        u[i][0] = a0.x * sc; u[i][1] = a0.y * sc;
        u[i][2] = a0.z * sc; u[i][3] = a0.w * sc;
        u[i][4] = a1.x * sc; u[i][5] = a1.y * sc;
        u[i][6] = a1.z * sc; u[i][7] = a1.w * sc;
    }
    if (tid < 256) { Rl[tid] = 0.f; Cl[tid] = 0.f; }
    __syncthreads();

#pragma unroll 1
    for (int it = 0; it < 2; ++it) {
        const bool even = (it & 1) == 0;
        float sm[8], ss[8];
        if (even) {
            float r[8];
#pragma unroll
            for (int i = 0; i < 8; ++i) r[i] = Rl[ta*8 + i];
#pragma unroll
            for (int j = 0; j < 8; ++j) {
                float m = u[0][j] - r[0];
#pragma unroll
                for (int i = 1; i < 8; ++i) m = fmaxf(m, u[i][j] - r[i]);
                float s0 = 0.f, s1 = 0.f;
#pragma unroll
                for (int i = 0; i < 8; i += 2) {
                    s0 += fexp2(u[i][j] - r[i] - m);
                    s1 += fexp2(u[i+1][j] - r[i+1] - m);
                }
                sm[j] = m; ss[j] = s0 + s1;
            }
        } else {
            float c[8];
#pragma unroll
            for (int j = 0; j < 8; ++j) c[j] = Cl[tb*8 + j];
#pragma unroll
            for (int i = 0; i < 8; ++i) {
                float m = u[i][0] - c[0];
#pragma unroll
                for (int j = 1; j < 8; ++j) m = fmaxf(m, u[i][j] - c[j]);
                float s0 = 0.f, s1 = 0.f;
#pragma unroll
                for (int j = 0; j < 8; j += 2) {
                    s0 += fexp2(u[i][j] - c[j] - m);
                    s1 += fexp2(u[i][j+1] - c[j+1] - m);
                }
                sm[i] = m; ss[i] = s0 + s1;
            }
        }
        {
            float* mrow = even ? &pm[ta][tb*8] : &pm[tb][ta*8];
            float* srow = even ? &ps[ta][tb*8] : &ps[tb][ta*8];
            ((float4*)mrow)[0] = make_float4(sm[0], sm[1], sm[2], sm[3]);
            ((float4*)mrow)[1] = make_float4(sm[4], sm[5], sm[6], sm[7]);
            ((float4*)srow)[0] = make_float4(ss[0], ss[1], ss[2], ss[3]);
            ((float4*)srow)[1] = make_float4(ss[4], ss[5], ss[6], ss[7]);
        }
        __syncthreads();
        float M = pm[sub*8][line4];
        float S = ps[sub*8][line4];
#pragma unroll
        for (int k = 1; k < 8; ++k) {
            float m2 = pm[sub*8 + k][line4];
            float s2 = ps[sub*8 + k][line4];
            float nm = fmaxf(M, m2);
            S = S * fexp2(M - nm) + s2 * fexp2(m2 - nm);
            M = nm;
        }
#pragma unroll
        for (int d = 1; d <= 2; d <<= 1) {
            float m2 = __shfl_xor(M, d);
            float s2 = __shfl_xor(S, d);
            float nm = fmaxf(M, m2);
            S = S * fexp2(M - nm) + s2 * fexp2(m2 - nm);
            M = nm;
        }
        if (sub == 0) {
            float l = M + flog2(S);
            if (even) Cl[line4] = l; else Rl[line4] = l;
        }
        __syncthreads();
    }

#pragma unroll 1
    for (int it = 2; it < 20; ++it) {
        const bool even = (it & 1) == 0;
        float r[8], c[8], ss[8];
#pragma unroll
        for (int i = 0; i < 8; ++i) r[i] = Rl[ta*8 + i];
#pragma unroll
        for (int j = 0; j < 8; ++j) c[j] = Cl[tb*8 + j];
        if (even) {
#pragma unroll
            for (int j = 0; j < 8; ++j) {
                float s0 = 0.f, s1 = 0.f;
#pragma unroll
                for (int i = 0; i < 8; i += 2) {
                    s0 += fexp2(u[i][j] - r[i] - c[j]);
                    s1 += fexp2(u[i+1][j] - r[i+1] - c[j]);
                }
                ss[j] = s0 + s1;
            }
        } else {
#pragma unroll
            for (int i = 0; i < 8; ++i) {
                float s0 = 0.f, s1 = 0.f;
#pragma unroll
                for (int j = 0; j < 8; j += 2) {
                    s0 += fexp2(u[i][j] - c[j] - r[i]);
                    s1 += fexp2(u[i][j+1] - c[j+1] - r[i]);
                }
                ss[i] = s0 + s1;
            }
        }
        {
            float* srow = even ? &ps[ta][tb*8] : &ps[tb][ta*8];
            ((float4*)srow)[0] = make_float4(ss[0], ss[1], ss[2], ss[3]);
            ((float4*)srow)[1] = make_float4(ss[4], ss[5], ss[6], ss[7]);
        }
        __syncthreads();
        float S = 0.f;
#pragma unroll
        for (int k = 0; k < 8; ++k) S += ps[sub*8 + k][line4];
        S += __shfl_xor(S, 1);
        S += __shfl_xor(S, 2);
        if (sub == 0) {
            float d = flog2(S);
            if (even) Cl[line4] += d; else Rl[line4] += d;
        }
        __syncthreads();
    }

    float r[8], c[8];
#pragma unroll
    for (int i = 0; i < 8; ++i) r[i] = Rl[ta*8 + i];
#pragma unroll
    for (int j = 0; j < 8; ++j) c[j] = Cl[tb*8 + j];
#pragma unroll
    for (int i = 0; i < 8; ++i) {
        int a = ta*8 + i;
#pragma unroll
        for (int j = 0; j < 8; ++j) {
            out[((size_t)(a*256 + tb*8 + j) << 6) + 63] =
                fexp2(u[i][j] - r[i] - c[j]);
        }
    }
}

extern "C" void kernel_launch(void* const* d_in, const int* in_sizes, int n_in,
                              void* d_out, int out_size, void* d_ws, size_t ws_size,
                              hipStream_t stream)
{
    const float* K_value = (const float*)d_in[0];
    const int*   K_index = (const int*)d_in[1];
    const float* A_value = (const float*)d_in[2];
    const int*   A_index = (const int*)d_in[3];
    const float* x   = (const float*)d_in[4];
    const float* Wn1 = (const float*)d_in[5];
    const float* bn1 = (const float*)d_in[6];
    const float* Wn2 = (const float*)d_in[7];
    const float* bn2 = (const float*)d_in[8];
    const float* Ws1 = (const float*)d_in[9];
    const float* bs1 = (const float*)d_in[10];
    const float* Ws2 = (const float*)d_in[11];
    const float* bs2 = (const float*)d_in[12];
    const float* Wc  = (const float*)d_in[13];
    const float* bc  = (const float*)d_in[14];

    int nnzK = in_sizes[0];
    int nnzA = in_sizes[2];
    int n    = in_sizes[4] / FI;   // 65536

    const int* rowsK = K_index;            const int* colsK = K_index + nnzK;
    const int* rowsA = A_index;            const int* colsA = A_index + nnzA;

    float* outf = (float*)d_out;
    char*  ws   = (char*)d_ws;
    float* bufA = (float*)ws;                         // 16MB: x1, later x2
    float* x3   = bufA + (size_t)n * FP;              // 256KB
    int*   ptrK = (int*)(x3 + n);                     // 256KB
    int*   ptrA = ptrK + n;                           // 256KB (adjacent -> 1 memset)
    int2*  sdatK = (int2*)(ptrA + n);                 // 8MB
    int2*  sdatA = sdatK + nnzK;                      // 4MB

    size_t need1 = ((size_t)n * FP + 3 * (size_t)n) * 4
                 + ((size_t)nnzK + nnzA) * 8;         // fused: ~28.75MB
    size_t need2 = ((size_t)n * FP + 2 * (size_t)n) * 4
                 + (size_t)nnzK * 8;                  // sequential: ~24.5MB (proven fits)

    // 1. n_func MLP -> bufA (x1, padded to 64)
    k_mlp_n<<<(n + 255) / 256, 256, 0, stream>>>(x, Wn1, bn1, Wn2, bn2, bufA, n);

    if (ws_size >= need1 && n == 65536) {
        // ---- tier 1: fused CSR builds ----
        (void)hipMemsetAsync(ptrK, 0, 2 * (size_t)n * 4, stream);
        int total = nnzK + nnzA;
        k_hist2<<<2048, 256, 0, stream>>>(rowsK, rowsA, ptrK, ptrA, nnzK, nnzA);
        k_scan2<<<2, 1024, 0, stream>>>(ptrK, ptrA);
        k_scatter2<<<2048, 256, 0, stream>>>(rowsK, colsK, K_value,
                                             rowsA, colsA, A_value,
                                             ptrK, ptrA, sdatK, sdatA, nnzK, nnzA);
        (void)total;
        k_gather<<<(n + 3) / 4, 256, 0, stream>>>(ptrK, sdatK, bufA, outf, n);
        k_gather<<<(n + 3) / 4, 256, 0, stream>>>(ptrA, sdatA, outf, bufA, n);
    } else if (ws_size >= need2 && n == 65536) {
        // ---- tier 2: sequential CSR (round-7 proven path; reuse ptrK/sdatK) ----
        (void)hipMemsetAsync(ptrK, 0, (size_t)n * 4, stream);
        k_hist<<<2048, 256, 0, stream>>>(rowsK, ptrK, nnzK);
        k_scan2<<<1, 1024, 0, stream>>>(ptrK, ptrK);
        k_scatter<<<2048, 256, 0, stream>>>(rowsK, colsK, K_value, ptrK, sdatK, nnzK);
        k_gather<<<(n + 3) / 4, 256, 0, stream>>>(ptrK, sdatK, bufA, outf, n);
        (void)hipMemsetAsync(ptrK, 0, (size_t)n * 4, stream);
        k_hist<<<2048, 256, 0, stream>>>(rowsA, ptrK, nnzA);
        k_scan2<<<1, 1024, 0, stream>>>(ptrK, ptrK);
        k_scatter<<<2048, 256, 0, stream>>>(rowsA, colsA, A_value, ptrK, sdatK, nnzA);
        k_gather<<<(n + 3) / 4, 256, 0, stream>>>(ptrK, sdatK, outf, bufA, n);
    } else {
        // ---- tier 3: atomic scatter fallback ----
        (void)hipMemsetAsync(outf, 0, (size_t)n * FP * 4, stream);
        int blocks1 = (nnzK + 4 * NZPW - 1) / (4 * NZPW);
        k_spmm<<<blocks1, 256, 0, stream>>>(rowsK, colsK, K_value, bufA, outf, nnzK);
        (void)hipMemsetAsync(bufA, 0, (size_t)n * FP * 4, stream);
        int blocks2 = (nnzA + 4 * NZPW - 1) / (4 * NZPW);
        k_spmm<<<blocks2, 256, 0, stream>>>(rowsA, colsA, A_value, outf, bufA, nnzA);
    }

    // combine: self-MLP + x2(bufA), write out[:, :63], classifier -> x3
    k_combine<<<(n + 255) / 256, 256, 0, stream>>>(x, Ws1, bs1, Ws2, bs2, Wc, bc,
                                                   bufA, outf, x3, n);
    // sinkhorn -> out[:, 63]
    k_sinkhorn<<<1, 1024, 0, stream>>>(x3, outf);
}